// Round 16
// baseline (393.239 us; speedup 1.0000x reference)
//
#include <hip/hip_runtime.h>
#include <math.h>

#define B_ 4
#define L_ 4096
#define D_ 1024
#define DG_ 256
#define NC_ 256         // number of chunks along L
#define CL_ 16          // chunk length (L_/NC_)
#define SEGL_ 8         // chunks per passB segment
#define NSEG_ 32        // NC_/SEGL_
#define PI_F 3.14159265358979323846f
#define LN_EPS_F 1e-5f

typedef __attribute__((ext_vector_type(8))) _Float16 f16x8;
typedef __attribute__((ext_vector_type(8))) short s16x8;
typedef __attribute__((ext_vector_type(4))) short s16x4;
typedef __attribute__((ext_vector_type(4))) float f32x4;

__device__ inline short f2h(float f) { return __builtin_bit_cast(short, (_Float16)f); }
__device__ inline float h2f(short s) { return (float)__builtin_bit_cast(_Float16, s); }

__device__ inline float ftanh(float x) {
    float e = __expf(2.0f * x);
    return 1.0f - 2.0f / (e + 1.0f);
}
__device__ inline void fsincos(float x, float* s, float* c) {
    *s = __sinf(x); *c = __cosf(x);
}

__device__ inline void gld16(const void* g, void* l) {
    __builtin_amdgcn_global_load_lds(
        (const __attribute__((address_space(1))) unsigned int*)g,
        (__attribute__((address_space(3))) unsigned int*)l, 16, 0, 0);
}

// ---------------------------------------------------------------------------
// conv_x: fp32 -> fp16, 8 elems/thread
// ---------------------------------------------------------------------------
__global__ __launch_bounds__(256)
void conv_x(const float* __restrict__ x, short* __restrict__ xh, int n8)
{
    int t = blockIdx.x * 256 + threadIdx.x;
    if (t >= n8) return;
    const float4* p = (const float4*)x + (size_t)t * 2;
    float4 a = p[0], b = p[1];
    s16x8 v;
    v[0] = f2h(a.x); v[1] = f2h(a.y); v[2] = f2h(a.z); v[3] = f2h(a.w);
    v[4] = f2h(b.x); v[5] = f2h(b.y); v[6] = f2h(b.z); v[7] = f2h(b.w);
    *(s16x8*)(xh + (size_t)t * 8) = v;
}

// ---------------------------------------------------------------------------
// csp_kernel: CSP[l][2d+{0,1}] = {cos, sin}(PP[l][d]) as fp16
// ---------------------------------------------------------------------------
__global__ __launch_bounds__(256)
void csp_kernel(const float* __restrict__ PP, short* __restrict__ CSP, int n4)
{
    int t = blockIdx.x * 256 + threadIdx.x;
    if (t >= n4) return;
    f32x4 p = *(const f32x4*)&PP[(size_t)t * 4];
    s16x8 o;
    #pragma unroll
    for (int j = 0; j < 4; ++j) {
        float s, c;
        fsincos(p[j], &s, &c);
        o[2 * j] = f2h(c);
        o[2 * j + 1] = f2h(s);
    }
    *(s16x8*)&CSP[(size_t)t * 8] = o;
}

// ---------------------------------------------------------------------------
// convT: W[1024][N] fp32 -> Th[N][1024] fp16, LDS-tiled transpose
// ---------------------------------------------------------------------------
__global__ __launch_bounds__(256)
void convT(const float* __restrict__ W, short* __restrict__ Th, int N)
{
    __shared__ float tile[64][65];
    const int n0 = blockIdx.x * 64, k0 = blockIdx.y * 64;
    const int t = threadIdx.x;
    const int r = t >> 4, c4 = (t & 15) * 4;

    #pragma unroll
    for (int i = 0; i < 4; ++i) {
        float4 v = *(const float4*)&W[(size_t)(k0 + r + i * 16) * N + n0 + c4];
        tile[r + i * 16][c4 + 0] = v.x;
        tile[r + i * 16][c4 + 1] = v.y;
        tile[r + i * 16][c4 + 2] = v.z;
        tile[r + i * 16][c4 + 3] = v.w;
    }
    __syncthreads();
    #pragma unroll
    for (int i = 0; i < 4; ++i) {
        const int n = r + i * 16;
        s16x4 o;
        o[0] = f2h(tile[c4 + 0][n]);
        o[1] = f2h(tile[c4 + 1][n]);
        o[2] = f2h(tile[c4 + 2][n]);
        o[3] = f2h(tile[c4 + 3][n]);
        *(s16x4*)&Th[(size_t)(n0 + n) * 1024 + k0 + c4] = o;
    }
}

// ---------------------------------------------------------------------------
// Sync macros: raw s_barrier; the only sched_barrier kept is rule #18's.
// ---------------------------------------------------------------------------
#define BARRIER() __builtin_amdgcn_s_barrier()
#define PRIO1() __builtin_amdgcn_s_setprio(1)
#define PRIO0() __builtin_amdgcn_s_setprio(0)
#define LGKM0() do { asm volatile("s_waitcnt lgkmcnt(0)" ::: "memory"); \
                     __builtin_amdgcn_sched_barrier(0); } while (0)
#define VMC(N) asm volatile("s_waitcnt vmcnt(" #N ")" ::: "memory")

#define DSR(dst, areg, OFS)                                              \
    asm volatile("ds_read_b128 %0, %1 offset:" OFS                       \
                 : "=v"(dst) : "v"(areg))

#define RDA4(areg)                                                       \
    DSR(af[0], areg, "0");    DSR(af[1], areg, "2048");                  \
    DSR(af[2], areg, "4096"); DSR(af[3], areg, "6144");
#define RDA4H(areg)                                                      \
    DSR(af[0], areg, "8192");  DSR(af[1], areg, "10240");                \
    DSR(af[2], areg, "12288"); DSR(af[3], areg, "14336");
#define RDB4S(areg)                                                      \
    DSR(bq[0], areg, "0");    DSR(bq[1], areg, "2048");                  \
    DSR(bq[2], areg, "4096"); DSR(bq[3], areg, "6144");

#define MF2(MG)                                                          \
    _Pragma("unroll") for (int i_ = 0; i_ < 4; ++i_)                     \
    _Pragma("unroll") for (int n_ = 0; n_ < 4; ++n_)                     \
        acc[(MG)*4 + i_][n_] = __builtin_amdgcn_mfma_f32_16x16x32_f16(   \
            af[i_], bq[n_], acc[(MG)*4 + i_][n_], 0, 0, 0);

// ---------------------------------------------------------------------------
// 256x256 MFMA fp16 GEMM v10 — m201-faithful phases with counted vmcnt.
// Phase order per BK=64 tile: (mg0,k0)(mg1,k0)(mg0,k1)(mg1,k1); bq[k] is
// register-held across the mg pair.  Staging of tile t+1 is spread 2 gld per
// phase in slab order B01, B23, A02, A13; sync only at ph0/ph1 as
// {vmcnt(COUNTED); barrier} — at ph0 the needed slabs (all-B + A02) are
// exactly the oldest 6 of 8 in-flight (vmcnt(2)); at ph1 (A13) the oldest of
// 4 (vmcnt(2)); ph2/ph3 need no sync (sources landed at ph0's barrier, WAR
// covered by it).  Last odd tile: ph1 -> vmcnt(0).  Never drains fresh loads.
// EPI 3: +X residual -> fp32; 4: fused QKV (tanh*pi / tanh*pi / plain)
// ---------------------------------------------------------------------------
template<int EPI, typename OT>
__global__ __launch_bounds__(512, 2)
void mgemm256(const short* __restrict__ A, const short* __restrict__ Bt,
              const float* __restrict__ X, OT* __restrict__ out0,
              short* __restrict__ out1, short* __restrict__ out2,
              const float* __restrict__ b0, const float* __restrict__ b1,
              const float* __restrict__ b2, int M, int N, int K)
{
    extern __shared__ char lds[];   // 131072: buf0/buf1 x (A 32KB + B 32KB)

    const int tid = threadIdx.x;
    const int w = tid >> 6, l = tid & 63;
    const int wr = w >> 2, wc = w & 3;          // 2 x 4 wave grid
    const int fr = l & 15, kb = l >> 4;
    const int bm = blockIdx.x * 256, bn = blockIdx.y * 256;
    const int np = K >> 7;                      // K-tile pairs

    const int s = fr & 7;
    const int cK0 = (((s >> 2) & 1) << 6) | (((kb ^ s) & 3) << 4);
    const int aA0 = (wr << 14) + fr * 128 + cK0;
    const int aA1 = aA0 ^ 64;
    const int aB0 = 32768 + ((wc >> 1) << 14) + ((wc & 1) * 64 + fr) * 128 + cK0;
    const int aB1 = aB0 ^ 64;
    const int aA0o = aA0 + 65536, aA1o = aA1 + 65536;
    const int aB0o = aB0 + 65536, aB1o = aB1 + 65536;

    const int p0 = tid * 16;
    const int sr = p0 >> 7;
    const int sc = (p0 & 127) ^ ((sr & 7) << 4);
    const short* gA = A  + (size_t)(bm + sr) * K + (sc >> 1);
    const short* gB = Bt + (size_t)(bn + sr) * K + (sc >> 1);
    char* ldst = lds + (w << 10);
    const size_t q1 = (size_t)64 * K, q2 = 2 * q1, q3 = 3 * q1;

    f32x4 acc[8][4] = {};
    f16x8 af[4];
    f16x8 bq[4];

    // ---- prologue: stage tile0 into buf0 (8 loads) ----
    gld16(gA,      ldst);          gld16(gA + q1, ldst + 8192);
    gld16(gA + q2, ldst + 16384);  gld16(gA + q3, ldst + 24576);
    gld16(gB,      ldst + 32768);  gld16(gB + q1, ldst + 40960);
    gld16(gB + q2, ldst + 49152);  gld16(gB + q3, ldst + 57344);
    VMC(0);
    BARRIER();

    const short* gAn = gA + 64;     // tile (2p+1) column base
    const short* gBn = gB + 64;

    for (int pp = 0; pp < np; ++pp) {
        const bool nl = (pp + 1 < np);

        // ====== even tile (read buf0, stage t+1 -> buf1) — always stages ==
        // ph0: (mg0,k0) — needs all-B + A slabs 0,2 of buf0
        VMC(2);
        BARRIER();
        RDA4(aA0); RDB4S(aB0);
        gld16(gBn,      ldst + 98304);         gld16(gBn + q1, ldst + 98304 + 8192);
        LGKM0();
        PRIO1(); MF2(0); PRIO0();
        // ph1: (mg1,k0) — needs A slabs 1,3 of buf0
        VMC(2);
        BARRIER();
        RDA4H(aA0);
        gld16(gBn + q2, ldst + 98304 + 16384); gld16(gBn + q3, ldst + 98304 + 24576);
        LGKM0();
        PRIO1(); MF2(1); PRIO0();
        // ph2: (mg0,k1) — sources landed at ph0's barrier
        RDA4(aA1); RDB4S(aB1);
        gld16(gAn,      ldst + 65536);         gld16(gAn + q2, ldst + 65536 + 16384);
        LGKM0();
        PRIO1(); MF2(0); PRIO0();
        // ph3: (mg1,k1)
        RDA4H(aA1);
        gld16(gAn + q1, ldst + 65536 + 8192);  gld16(gAn + q3, ldst + 65536 + 24576);
        LGKM0();
        PRIO1(); MF2(1); PRIO0();

        // ====== odd tile (read buf1, stage t+2 -> buf0 when nl) ==========
        // ph0
        VMC(2);
        BARRIER();
        RDA4(aA0o); RDB4S(aB0o);
        if (nl) {
            gld16(gBn +      64, ldst + 32768); gld16(gBn + q1 + 64, ldst + 40960);
        }
        LGKM0();
        PRIO1(); MF2(0); PRIO0();
        // ph1
        if (nl) { VMC(2); } else { VMC(0); }
        BARRIER();
        RDA4H(aA0o);
        if (nl) {
            gld16(gBn + q2 + 64, ldst + 49152); gld16(gBn + q3 + 64, ldst + 57344);
        }
        LGKM0();
        PRIO1(); MF2(1); PRIO0();
        // ph2
        RDA4(aA1o); RDB4S(aB1o);
        if (nl) {
            gld16(gAn +      64, ldst);         gld16(gAn + q2 + 64, ldst + 16384);
        }
        LGKM0();
        PRIO1(); MF2(0); PRIO0();
        // ph3
        RDA4H(aA1o);
        if (nl) {
            gld16(gAn + q1 + 64, ldst + 8192);  gld16(gAn + q3 + 64, ldst + 24576);
        }
        LGKM0();
        PRIO1(); MF2(1); PRIO0();

        gAn += 128; gBn += 128;
    }

    // ---- epilogue: C/D layout col=lane&15, row=(lane>>4)*4+reg, nf inner --
    if constexpr (EPI == 4) {
        short* op; const float* bp; bool dt;
        if (bn < 1024)      { op = (short*)out0; bp = b0; dt = true;  }
        else if (bn < 2048) { op = out1;         bp = b1; dt = true;  }
        else                { op = out2;         bp = b2; dt = false; }
        const int cb = bn & 1023;
        float bc[4];
        #pragma unroll
        for (int nf = 0; nf < 4; ++nf) bc[nf] = bp[cb + wc * 64 + nf * 16 + fr];
        #pragma unroll
        for (int mf = 0; mf < 8; ++mf)
            #pragma unroll
            for (int rr = 0; rr < 4; ++rr) {
                const int row = bm + wr * 128 + mf * 16 + kb * 4 + rr;
                #pragma unroll
                for (int nf = 0; nf < 4; ++nf) {
                    const int cc = cb + wc * 64 + nf * 16 + fr;
                    float c = acc[mf][nf][rr] + bc[nf];
                    if (dt) c = ftanh(c) * PI_F;
                    op[(size_t)row * 1024 + cc] = f2h(c);
                }
            }
    } else {   // EPI == 3: +X residual -> fp32
        float bc[4];
        #pragma unroll
        for (int nf = 0; nf < 4; ++nf) bc[nf] = b0[bn + wc * 64 + nf * 16 + fr];
        #pragma unroll
        for (int mf = 0; mf < 8; ++mf)
            #pragma unroll
            for (int rr = 0; rr < 4; ++rr) {
                const int row = bm + wr * 128 + mf * 16 + kb * 4 + rr;
                #pragma unroll
                for (int nf = 0; nf < 4; ++nf) {
                    const int col = bn + wc * 64 + nf * 16 + fr;
                    float c = acc[mf][nf][rr] + bc[nf] + X[(size_t)row * N + col];
                    ((float*)out0)[(size_t)row * N + col] = c;
                }
            }
    }
}

// ---------------------------------------------------------------------------
// gemm128 — 128x128 tile, BK=64, 4 waves, 64KB LDS dbuf (2 blocks/CU).
// H-gate GEMM (EPI 5): gelu(acc+bg1).Wg2 -> fr-reduce -> atomicAdd gatep.
// ---------------------------------------------------------------------------
#define RDAF(areg)                                                       \
    DSR(af[0], areg, "0");    DSR(af[1], areg, "2048");                  \
    DSR(af[2], areg, "4096"); DSR(af[3], areg, "6144");
#define RDBF(areg)                                                       \
    DSR(bqs[0], areg, "0");    DSR(bqs[1], areg, "2048");                \
    DSR(bqs[2], areg, "4096"); DSR(bqs[3], areg, "6144");

#define MF16()                                                           \
    _Pragma("unroll") for (int i_ = 0; i_ < 4; ++i_)                     \
    _Pragma("unroll") for (int n_ = 0; n_ < 4; ++n_)                     \
        acc[i_][n_] = __builtin_amdgcn_mfma_f32_16x16x32_f16(            \
            af[i_], bqs[n_], acc[i_][n_], 0, 0, 0);

template<int EPI>
__global__ __launch_bounds__(256, 2)
void gemm128(const short* __restrict__ A, const short* __restrict__ Bt,
             const float* __restrict__ b0, const float* __restrict__ wg2p,
             float* __restrict__ gatep, int M, int N, int K)
{
    extern __shared__ char lds[];   // 65536

    const int tid = threadIdx.x;
    const int w = tid >> 6, l = tid & 63;
    const int wr = w >> 1, wc = w & 1;
    const int fr = l & 15, kb = l >> 4;
    const int bm = blockIdx.x * 128, bn = blockIdx.y * 128;

    const int s = fr & 7;
    const int cK0 = (((s >> 2) & 1) << 6) | (((kb ^ s) & 3) << 4);
    const int aA0e = (wr * 64 + fr) * 128 + cK0;
    const int aA1e = aA0e ^ 64;
    const int aB0e = 16384 + (wc * 64 + fr) * 128 + cK0;
    const int aB1e = aB0e ^ 64;
    const int aA0o = aA0e + 32768, aA1o = aA1e + 32768;
    const int aB0o = aB0e + 32768, aB1o = aB1e + 32768;

    const int p16 = tid * 16;
    const int sr = p16 >> 7;
    const int sc = (p16 & 127) ^ ((sr & 7) << 4);
    const short* gA = A  + (size_t)(bm + sr) * K + (sc >> 1);
    const short* gB = Bt + (size_t)(bn + sr) * K + (sc >> 1);
    char* ldA = lds + (w << 10);
    const size_t r32 = (size_t)32 * K;

    f32x4 acc[4][4] = {};
    f16x8 af[4], bqs[4];

    #pragma unroll
    for (int i = 0; i < 4; ++i) gld16(gA + i * r32, ldA + i * 4096);
    #pragma unroll
    for (int i = 0; i < 4; ++i) gld16(gB + i * r32, ldA + 16384 + i * 4096);
    VMC(0);
    BARRIER();

    const short* gAt = gA;
    const short* gBt = gB;
    const int np = K >> 7;

    for (int pp = 0; pp < np; ++pp) {
        const bool nl = (pp + 1 < np);

        RDAF(aA0e); RDBF(aB0e);
        #pragma unroll
        for (int i = 0; i < 4; ++i) gld16(gAt + 64 + i * r32, ldA + 32768 + i * 4096);
        LGKM0();
        PRIO1(); MF16(); PRIO0();
        RDAF(aA1e); RDBF(aB1e);
        #pragma unroll
        for (int i = 0; i < 4; ++i) gld16(gBt + 64 + i * r32, ldA + 49152 + i * 4096);
        LGKM0();
        PRIO1(); MF16(); PRIO0();
        VMC(0);
        BARRIER();

        RDAF(aA0o); RDBF(aB0o);
        if (nl) {
            #pragma unroll
            for (int i = 0; i < 4; ++i) gld16(gAt + 128 + i * r32, ldA + i * 4096);
        }
        LGKM0();
        PRIO1(); MF16(); PRIO0();
        RDAF(aA1o); RDBF(aB1o);
        if (nl) {
            #pragma unroll
            for (int i = 0; i < 4; ++i) gld16(gBt + 128 + i * r32, ldA + 16384 + i * 4096);
        }
        LGKM0();
        PRIO1(); MF16(); PRIO0();
        if (nl) {
            VMC(0);
            BARRIER();
        }
        gAt += 128; gBt += 128;
    }

    float bg[4], wg[4];
    #pragma unroll
    for (int nf = 0; nf < 4; ++nf) {
        const int cl = bn + wc * 64 + nf * 16 + fr;
        bg[nf] = b0[cl];
        wg[nf] = wg2p[cl];
    }
    #pragma unroll
    for (int mf = 0; mf < 4; ++mf)
        #pragma unroll
        for (int rr = 0; rr < 4; ++rr) {
            const int row = bm + wr * 64 + mf * 16 + kb * 4 + rr;
            float part = 0.f;
            #pragma unroll
            for (int nf = 0; nf < 4; ++nf) {
                float c = acc[mf][nf][rr] + bg[nf];
                float tt = 0.7978845608028654f * (c + 0.044715f * c * c * c);
                float g = 0.5f * c * (1.0f + ftanh(tt));
                part += g * wg[nf];
            }
            part += __shfl_xor(part, 1);
            part += __shfl_xor(part, 2);
            part += __shfl_xor(part, 4);
            part += __shfl_xor(part, 8);
            if (fr == 0) atomicAdd(&gatep[row], part);
        }
}

// ---------------------------------------------------------------------------
// Pass A: per-chunk sums; CSP table for cos/sin(pp). grid = B*NC = 1024.
// ---------------------------------------------------------------------------
__global__ __launch_bounds__(256)
void passA(const short* __restrict__ V, const short* __restrict__ KP,
           const short* __restrict__ CSP, f32x4* __restrict__ SI)
{
    const int bid = blockIdx.x;          // b*NC + c
    const int b = bid >> 8, c = bid & 255;
    const int d0 = threadIdx.x * 4;

    f32x4 cr = {}, ci = {}, pr = {}, pi = {};
    const size_t base = ((size_t)b * L_ + (size_t)c * CL_) * D_ + d0;
    const size_t pcs  = ((size_t)c * CL_ * D_ + d0) * 2;
    for (int ll = 0; ll < CL_; ++ll) {
        s16x4 v4  = *(const s16x4*)&V [base + (size_t)ll * D_];
        s16x4 kp4 = *(const s16x4*)&KP[base + (size_t)ll * D_];
        s16x8 c8  = *(const s16x8*)&CSP[pcs + (size_t)ll * (D_ * 2)];
        #pragma unroll
        for (int j = 0; j < 4; ++j) {
            float v = h2f(v4[j]);
            float sk, ck;
            fsincos(h2f(kp4[j]), &sk, &ck);
            float cp = h2f(c8[2 * j]), sp = h2f(c8[2 * j + 1]);
            cr[j] += v * ck; ci[j] += v * sk;
            pr[j] += v * cp; pi[j] += v * sp;
        }
    }
    const size_t sidx = ((size_t)bid << 10) + d0;
    #pragma unroll
    for (int j = 0; j < 4; ++j) {
        f32x4 o = { cr[j], ci[j], pr[j], pi[j] };
        SI[sidx + j] = o;
    }
}

// ---------------------------------------------------------------------------
// Pass B1: exclusive scan within 8-chunk segments; emits segment sums.
// ---------------------------------------------------------------------------
__global__ __launch_bounds__(256)
void passB1(f32x4* __restrict__ SI, f32x4* __restrict__ STS)
{
    const int seg = blockIdx.x & (NSEG_ - 1);
    const int t = (blockIdx.x >> 5) * 256 + threadIdx.x;  // 0..B*D-1
    const int b = t >> 10, d = t & 1023;
    f32x4 run = {};
    #pragma unroll
    for (int i = 0; i < SEGL_; ++i) {
        const int c = seg * SEGL_ + i;
        const size_t idx = ((size_t)(b * NC_ + c) << 10) + d;
        f32x4 v = SI[idx];
        SI[idx] = run;
        run += v;
    }
    STS[((size_t)(b * NSEG_ + seg) << 10) + d] = run;
}

// ---------------------------------------------------------------------------
// Pass B2: exclusive scan of segment sums (32 per (b,d)).
// ---------------------------------------------------------------------------
__global__ __launch_bounds__(256)
void passB2(f32x4* __restrict__ STS)
{
    const int t = blockIdx.x * 256 + threadIdx.x;  // 0..B*D-1
    const int b = t >> 10, d = t & 1023;
    f32x4 run = {};
    #pragma unroll
    for (int seg = 0; seg < NSEG_; ++seg) {
        const size_t idx = ((size_t)(b * NSEG_ + seg) << 10) + d;
        f32x4 v = STS[idx];
        STS[idx] = run;
        run += v;
    }
}

// ---------------------------------------------------------------------------
// Pass C v2 — wave-per-chunk, barrier-free; pure-__shfl LN reduce; register
// prefetch of next-iter loads. grid = B*NC/4 blocks x 256 thr.
// ---------------------------------------------------------------------------
__global__ __launch_bounds__(256)
void passC(const short* __restrict__ V, const short* KP,
           const short* __restrict__ QP, const short* __restrict__ CSP,
           const float* __restrict__ gatep, const float* __restrict__ bg2,
           const f32x4* __restrict__ SI, const f32x4* __restrict__ STS,
           const float* __restrict__ ln_g, const float* __restrict__ ln_b,
           short* Yb)
{
    const int w = threadIdx.x >> 6, lane = threadIdx.x & 63;
    const int gw = blockIdx.x * 4 + w;          // chunk id 0..B*NC-1
    const int b = gw >> 8, c = gw & 255;
    const int d0 = lane * 16;

    const size_t sidx = ((size_t)gw << 10) + d0;
    const size_t tidx = ((size_t)(b * NSEG_ + (c >> 3)) << 10) + d0;
    float cr[16], ci[16], pr[16], pi[16];
    #pragma unroll
    for (int j = 0; j < 16; ++j) {
        f32x4 s0 = SI[sidx + j] + STS[tidx + j];
        cr[j] = s0[0]; ci[j] = s0[1]; pr[j] = s0[2]; pi[j] = s0[3];
    }
    float gl[16], bl[16];
    #pragma unroll
    for (int j = 0; j < 16; ++j) { gl[j] = ln_g[d0 + j]; bl[j] = ln_b[d0 + j]; }
    const float bg2v = bg2[0];

    const int lbase = c * CL_;
    size_t off = ((size_t)b * L_ + lbase) * D_ + d0;
    size_t cso = ((size_t)lbase * D_ + d0) * 2;

    s16x8 v8a, v8b, k8a, k8b, q8a, q8b, c8a, c8b, c8c, c8d;
    v8a = *(const s16x8*)&V [off];      v8b = *(const s16x8*)&V [off + 8];
    k8a = *(const s16x8*)&KP[off];      k8b = *(const s16x8*)&KP[off + 8];
    q8a = *(const s16x8*)&QP[off];      q8b = *(const s16x8*)&QP[off + 8];
    c8a = *(const s16x8*)&CSP[cso];     c8b = *(const s16x8*)&CSP[cso + 8];
    c8c = *(const s16x8*)&CSP[cso + 16];c8d = *(const s16x8*)&CSP[cso + 24];
    float gpre = gatep[b * L_ + lbase];

    for (int l0 = 0; l0 < CL_; ++l0) {
        const int ll = lbase + l0;
        const size_t offn = off + D_;
        const size_t cson = cso + D_ * 2;
        s16x8 v8an = v8a, v8bn = v8b, k8an = k8a, k8bn = k8b;
        s16x8 q8an = q8a, q8bn = q8b, c8an = c8a, c8bn = c8b, c8cn = c8c, c8dn = c8d;
        float gpn = gpre;
        if (l0 + 1 < CL_) {
            v8an = *(const s16x8*)&V [offn];      v8bn = *(const s16x8*)&V [offn + 8];
            k8an = *(const s16x8*)&KP[offn];      k8bn = *(const s16x8*)&KP[offn + 8];
            q8an = *(const s16x8*)&QP[offn];      q8bn = *(const s16x8*)&QP[offn + 8];
            c8an = *(const s16x8*)&CSP[cson];     c8bn = *(const s16x8*)&CSP[cson + 8];
            c8cn = *(const s16x8*)&CSP[cson + 16];c8dn = *(const s16x8*)&CSP[cson + 24];
            gpn  = gatep[b * L_ + ll + 1];
        }

        const float gv = 1.0f / (1.0f + __expf(-(gpre + bg2v)));
        const float rs_pos = rsqrtf((float)(ll + 1));

        float u[16];
        float sm = 0.f, s2 = 0.f;
        #pragma unroll
        for (int j = 0; j < 16; ++j) {
            const short vs = (j < 8) ? v8a[j & 7] : v8b[j & 7];
            const short ks = (j < 8) ? k8a[j & 7] : k8b[j & 7];
            const short qs = (j < 8) ? q8a[j & 7] : q8b[j & 7];
            const int cj = 2 * j;
            const short cps = (cj < 8) ? c8a[cj & 7]
                             : (cj < 16) ? c8b[cj & 7]
                             : (cj < 24) ? c8c[cj & 7] : c8d[cj & 7];
            const short sps = (cj + 1 < 8) ? c8a[(cj + 1) & 7]
                             : (cj + 1 < 16) ? c8b[(cj + 1) & 7]
                             : (cj + 1 < 24) ? c8c[(cj + 1) & 7] : c8d[(cj + 1) & 7];
            float v = h2f(vs);
            float sk, ck, sq, cq;
            fsincos(h2f(ks), &sk, &ck);
            fsincos(h2f(qs), &sq, &cq);
            float cp = h2f(cps), sp = h2f(sps);
            cr[j] += v * ck; ci[j] += v * sk;
            pr[j] += v * cp; pi[j] += v * sp;
            float content = cr[j] * cq + ci[j] * sq;
            float posr    = pr[j] * cp + pi[j] * sp;
            u[j] = (gv * content + (1.0f - gv) * posr) * rs_pos;
            sm += u[j]; s2 += u[j] * u[j];
        }

        #pragma unroll
        for (int o = 32; o; o >>= 1) {
            sm += __shfl_down(sm, o);
            s2 += __shfl_down(s2, o);
        }
        sm = __shfl(sm, 0);
        s2 = __shfl(s2, 0);
        const float mu  = sm * (1.0f / D_);
        const float var = s2 * (1.0f / D_) - mu * mu;
        const float rsv = rsqrtf(var + LN_EPS_F);
        s16x8 yo0, yo1;
        #pragma unroll
        for (int j = 0; j < 8; ++j)
            yo0[j] = f2h((u[j] - mu) * rsv * gl[j] + bl[j]);
        #pragma unroll
        for (int j = 0; j < 8; ++j)
            yo1[j] = f2h((u[8 + j] - mu) * rsv * gl[8 + j] + bl[8 + j]);
        *(s16x8*)&Yb[off] = yo0;
        *(s16x8*)&Yb[off + 8] = yo1;

        off = offn; cso = cson;
        v8a = v8an; v8b = v8bn; k8a = k8an; k8b = k8bn;
        q8a = q8an; q8b = q8bn;
        c8a = c8an; c8b = c8bn; c8c = c8cn; c8d = c8dn;
        gpre = gpn;
    }
}

// ---------------------------------------------------------------------------
extern "C" void kernel_launch(void* const* d_in, const int* in_sizes, int n_in,
                              void* d_out, int out_size, void* d_ws, size_t ws_size,
                              hipStream_t stream)
{
    const float* x    = (const float*)d_in[0];
    const float* Wk   = (const float*)d_in[1];
    const float* bk   = (const float*)d_in[2];
    const float* Wq   = (const float*)d_in[3];
    const float* bq   = (const float*)d_in[4];
    const float* Wv   = (const float*)d_in[5];
    const float* bv   = (const float*)d_in[6];
    const float* ln_g = (const float*)d_in[7];
    const float* ln_b = (const float*)d_in[8];
    const float* Wo   = (const float*)d_in[9];
    const float* bo   = (const float*)d_in[10];
    const float* Wg1  = (const float*)d_in[11];
    const float* bg1  = (const float*)d_in[12];
    const float* Wg2  = (const float*)d_in[13];
    const float* bg2  = (const float*)d_in[14];
    const float* PP   = (const float*)d_in[15];

    float* out = (float*)d_out;

    const size_t BLD   = (size_t)B_ * L_ * D_;           // 16,777,216
    const size_t SZ_X  = BLD * 2;                        // 33,554,432
    const size_t SZ_R1 = (size_t)B_ * L_ * DG_ * 2;      //  8,388,608
    const size_t SZ_G1 = (size_t)D_ * DG_ * 2;           //    524,288
    const size_t SZ_GT = (size_t)B_ * L_ * 4;            //     65,536
    const size_t NEED  = SZ_X + SZ_R1 + SZ_G1 + 3 * SZ_X + SZ_GT;  // ~143.2MB
    if (ws_size < NEED) {
        hipMemcpyAsync(d_out, d_in[0], BLD * sizeof(float),
                       hipMemcpyDeviceToDevice, stream);
        return;
    }

    char* wsb = (char*)d_ws;
    short* xh   = (short*)(wsb);                          // region0: fp16 x (32MiB)
    char*  r1   = wsb + SZ_X;
    short* Wcat = (short*)r1;                             // [3072][1024] fp16
    short* Wg1T = (short*)(r1 + SZ_R1);                   // [256][1024] fp16
    short* KP   = (short*)(r1 + SZ_R1 + SZ_G1);
    short* QP   = (short*)((char*)KP + SZ_X);
    short* V    = (short*)((char*)QP + SZ_X);
    float* gatep = (float*)((char*)V + SZ_X);             // gate_pre accumulators
    // aliases (dead regions):
    f32x4* SI   = (f32x4*)(wsb);                          // 16.78MB (xh dead)
    short* CSP  = (short*)(wsb + 16777216);               // 16.78MB (xh dead)
    short* WtO  = (short*)r1;                             //  2MB (Wcat dead)
    f32x4* STS  = (f32x4*)(r1 + 2097152);                 //  2MB (Wcat dead)
    short* Yb   = KP;                                     // passC writes over KP

    const int M = B_ * L_;
    dim3 blk(256);

    // 1. conversions (x, QKV weights, gate W1; Wo/CSP deferred into dead areas)
    conv_x<<<(int)(BLD / 8 / 256), blk, 0, stream>>>(x, xh, (int)(BLD / 8));
    dim3 gT(D_ / 64, 16);
    dim3 gTg(DG_ / 64, 16);
    convT<<<gT, blk, 0, stream>>>(Wk, Wcat + (size_t)0 * D_ * D_, D_);
    convT<<<gT, blk, 0, stream>>>(Wq, Wcat + (size_t)1 * D_ * D_, D_);
    convT<<<gT, blk, 0, stream>>>(Wv, Wcat + (size_t)2 * D_ * D_, D_);
    convT<<<gTg, blk, 0, stream>>>(Wg1, Wg1T, DG_);
    hipMemsetAsync(gatep, 0, SZ_GT, stream);

    // 2. fused QKV GEMM (256² v10), then H-gate GEMM
    dim3 gQKV(M / 256, 3072 / 256);
    hipLaunchKernelGGL((mgemm256<4, short>), gQKV, dim3(512), 131072, stream,
                       xh, Wcat, nullptr, KP, QP, V, bk, bq, bv, M, 3072, D_);
    dim3 gH(M / 128, DG_ / 128);
    hipLaunchKernelGGL((gemm128<5>), gH, blk, 65536, stream,
                       xh, Wg1T, bg1, Wg2, gatep, M, DG_, D_);

    // 3. deferred Wo conversion (into dead Wcat) + CSP table (into dead xh)
    convT<<<gT, blk, 0, stream>>>(Wo, WtO, D_);
    csp_kernel<<<(int)((size_t)L_ * D_ / 4 / 256), blk, 0, stream>>>(
        PP, CSP, (int)((size_t)L_ * D_ / 4));

    // 4. scans + fused LN (sigmoid applied in passC)
    passA<<<B_ * NC_, blk, 0, stream>>>(V, KP, CSP, SI);
    passB1<<<(B_ * D_ / 256) * NSEG_, blk, 0, stream>>>(SI, STS);
    passB2<<<B_ * D_ / 256, blk, 0, stream>>>(STS);
    passC<<<B_ * NC_ / 4, blk, 0, stream>>>(V, KP, QP, CSP, gatep, bg2, SI, STS,
                                            ln_g, ln_b, Yb);

    // 5. output GEMM (+ residual), 64x4 grid = 1 exact round
    dim3 gO(M / 256, D_ / 256);
    hipLaunchKernelGGL((mgemm256<3, float>), gO, dim3(512), 131072, stream,
                       Yb, WtO, x, out, nullptr, nullptr, bo, nullptr, nullptr,
                       M, D_, D_);
}

// Round 17
// 283.050 us; speedup vs baseline: 1.3893x; 1.3893x over previous
//
#include <hip/hip_runtime.h>
#include <math.h>

#define B_ 4
#define L_ 4096
#define D_ 1024
#define DG_ 256
#define NC_ 256         // number of chunks along L
#define CL_ 16          // chunk length (L_/NC_)
#define SEGL_ 8         // chunks per passB segment
#define NSEG_ 32        // NC_/SEGL_
#define PI_F 3.14159265358979323846f
#define LN_EPS_F 1e-5f

typedef __attribute__((ext_vector_type(8))) _Float16 f16x8;
typedef __attribute__((ext_vector_type(8))) short s16x8;
typedef __attribute__((ext_vector_type(4))) short s16x4;
typedef __attribute__((ext_vector_type(4))) float f32x4;

__device__ inline short f2h(float f) { return __builtin_bit_cast(short, (_Float16)f); }
__device__ inline float h2f(short s) { return (float)__builtin_bit_cast(_Float16, s); }

__device__ inline float ftanh(float x) {
    float e = __expf(2.0f * x);
    return 1.0f - 2.0f / (e + 1.0f);
}
__device__ inline void fsincos(float x, float* s, float* c) {
    *s = __sinf(x); *c = __cosf(x);
}

__device__ inline void gld16(const void* g, void* l) {
    __builtin_amdgcn_global_load_lds(
        (const __attribute__((address_space(1))) unsigned int*)g,
        (__attribute__((address_space(3))) unsigned int*)l, 16, 0, 0);
}

// ---------------------------------------------------------------------------
// conv_x: fp32 -> fp16, 8 elems/thread
// ---------------------------------------------------------------------------
__global__ __launch_bounds__(256)
void conv_x(const float* __restrict__ x, short* __restrict__ xh, int n8)
{
    int t = blockIdx.x * 256 + threadIdx.x;
    if (t >= n8) return;
    const float4* p = (const float4*)x + (size_t)t * 2;
    float4 a = p[0], b = p[1];
    s16x8 v;
    v[0] = f2h(a.x); v[1] = f2h(a.y); v[2] = f2h(a.z); v[3] = f2h(a.w);
    v[4] = f2h(b.x); v[5] = f2h(b.y); v[6] = f2h(b.z); v[7] = f2h(b.w);
    *(s16x8*)(xh + (size_t)t * 8) = v;
}

// ---------------------------------------------------------------------------
// csp_kernel: CSP[l][2d+{0,1}] = {cos, sin}(PP[l][d]) as fp16
// ---------------------------------------------------------------------------
__global__ __launch_bounds__(256)
void csp_kernel(const float* __restrict__ PP, short* __restrict__ CSP, int n4)
{
    int t = blockIdx.x * 256 + threadIdx.x;
    if (t >= n4) return;
    f32x4 p = *(const f32x4*)&PP[(size_t)t * 4];
    s16x8 o;
    #pragma unroll
    for (int j = 0; j < 4; ++j) {
        float s, c;
        fsincos(p[j], &s, &c);
        o[2 * j] = f2h(c);
        o[2 * j + 1] = f2h(s);
    }
    *(s16x8*)&CSP[(size_t)t * 8] = o;
}

// ---------------------------------------------------------------------------
// convT: W[1024][N] fp32 -> Th[N][1024] fp16, LDS-tiled transpose
// ---------------------------------------------------------------------------
__global__ __launch_bounds__(256)
void convT(const float* __restrict__ W, short* __restrict__ Th, int N)
{
    __shared__ float tile[64][65];
    const int n0 = blockIdx.x * 64, k0 = blockIdx.y * 64;
    const int t = threadIdx.x;
    const int r = t >> 4, c4 = (t & 15) * 4;

    #pragma unroll
    for (int i = 0; i < 4; ++i) {
        float4 v = *(const float4*)&W[(size_t)(k0 + r + i * 16) * N + n0 + c4];
        tile[r + i * 16][c4 + 0] = v.x;
        tile[r + i * 16][c4 + 1] = v.y;
        tile[r + i * 16][c4 + 2] = v.z;
        tile[r + i * 16][c4 + 3] = v.w;
    }
    __syncthreads();
    #pragma unroll
    for (int i = 0; i < 4; ++i) {
        const int n = r + i * 16;
        s16x4 o;
        o[0] = f2h(tile[c4 + 0][n]);
        o[1] = f2h(tile[c4 + 1][n]);
        o[2] = f2h(tile[c4 + 2][n]);
        o[3] = f2h(tile[c4 + 3][n]);
        *(s16x4*)&Th[(size_t)(n0 + n) * 1024 + k0 + c4] = o;
    }
}

// ---------------------------------------------------------------------------
// Sync macros: raw s_barrier; the only sched_barrier kept is rule #18's.
// ---------------------------------------------------------------------------
#define BARRIER() __builtin_amdgcn_s_barrier()
#define PRIO1() __builtin_amdgcn_s_setprio(1)
#define PRIO0() __builtin_amdgcn_s_setprio(0)
#define LGKM0() do { asm volatile("s_waitcnt lgkmcnt(0)" ::: "memory"); \
                     __builtin_amdgcn_sched_barrier(0); } while (0)
#define VMC(N) asm volatile("s_waitcnt vmcnt(" #N ")" ::: "memory")

#define DSR(dst, areg, OFS)                                              \
    asm volatile("ds_read_b128 %0, %1 offset:" OFS                       \
                 : "=v"(dst) : "v"(areg))

#define RDA4(areg)                                                       \
    DSR(af[0], areg, "0");    DSR(af[1], areg, "2048");                  \
    DSR(af[2], areg, "4096"); DSR(af[3], areg, "6144");
#define RDA4H(areg)                                                      \
    DSR(af[0], areg, "8192");  DSR(af[1], areg, "10240");                \
    DSR(af[2], areg, "12288"); DSR(af[3], areg, "14336");
#define RDB4(areg, KK)                                                   \
    DSR(bq[0][KK], areg, "0");    DSR(bq[1][KK], areg, "2048");          \
    DSR(bq[2][KK], areg, "4096"); DSR(bq[3][KK], areg, "6144");

#define MF(MG, KK)                                                       \
    _Pragma("unroll") for (int i_ = 0; i_ < 4; ++i_)                     \
    _Pragma("unroll") for (int n_ = 0; n_ < 4; ++n_)                     \
        acc[(MG)*4 + i_][n_] = __builtin_amdgcn_mfma_f32_16x16x32_f16(   \
            af[i_], bq[n_][KK], acc[(MG)*4 + i_][n_], 0, 0, 0);

// ---------------------------------------------------------------------------
// 256x256 MFMA fp16 GEMM v9 — ONE barrier per K-tile (pure double-buffer).
// Best-measured variant (r15: QKV 113 µs, MfmaUtil 40%).  Per tile:
// {ph0 reads + stage B(t+1) -> nxt; ph1 reads + stage A(t+1) -> nxt;
// ph2-3 reads}; boundary = vmcnt(0)+barrier (exact: all 8 in-flight loads
// are needed there; issue-to-need slack ~2 phases >= HBM latency).
// EPI 3: +X residual -> fp32; 4: fused QKV (tanh*pi / tanh*pi / plain)
// ---------------------------------------------------------------------------
template<int EPI, typename OT>
__global__ __launch_bounds__(512, 2)
void mgemm256(const short* __restrict__ A, const short* __restrict__ Bt,
              const float* __restrict__ X, OT* __restrict__ out0,
              short* __restrict__ out1, short* __restrict__ out2,
              const float* __restrict__ b0, const float* __restrict__ b1,
              const float* __restrict__ b2, int M, int N, int K)
{
    extern __shared__ char lds[];   // 131072: buf0/buf1 x (A 32KB + B 32KB)

    const int tid = threadIdx.x;
    const int w = tid >> 6, l = tid & 63;
    const int wr = w >> 2, wc = w & 3;          // 2 x 4 wave grid
    const int fr = l & 15, kb = l >> 4;
    const int bm = blockIdx.x * 256, bn = blockIdx.y * 256;
    const int np = K >> 7;                      // K-tile pairs

    const int s = fr & 7;
    const int cK0 = (((s >> 2) & 1) << 6) | (((kb ^ s) & 3) << 4);
    const int aA0 = (wr << 14) + fr * 128 + cK0;
    const int aA1 = aA0 ^ 64;
    const int aB0 = 32768 + ((wc >> 1) << 14) + ((wc & 1) * 64 + fr) * 128 + cK0;
    const int aB1 = aB0 ^ 64;
    const int aA0o = aA0 + 65536, aA1o = aA1 + 65536;
    const int aB0o = aB0 + 65536, aB1o = aB1 + 65536;

    const int p0 = tid * 16;
    const int sr = p0 >> 7;
    const int sc = (p0 & 127) ^ ((sr & 7) << 4);
    const short* gA = A  + (size_t)(bm + sr) * K + (sc >> 1);
    const short* gB = Bt + (size_t)(bn + sr) * K + (sc >> 1);
    char* ldst = lds + (w << 10);
    const size_t q1 = (size_t)64 * K, q2 = 2 * q1, q3 = 3 * q1;

    f32x4 acc[8][4] = {};
    f16x8 af[4];
    f16x8 bq[4][2];

    // ---- prologue: stage tile0 into buf0 (8 loads) ----
    gld16(gA,      ldst);          gld16(gA + q1, ldst + 8192);
    gld16(gA + q2, ldst + 16384);  gld16(gA + q3, ldst + 24576);
    gld16(gB,      ldst + 32768);  gld16(gB + q1, ldst + 40960);
    gld16(gB + q2, ldst + 49152);  gld16(gB + q3, ldst + 57344);
    VMC(0);
    BARRIER();

    const short* gAn = gA + 64;     // tile (2p+1) column base
    const short* gBn = gB + 64;

    for (int pp = 0; pp < np; ++pp) {
        const bool nl = (pp + 1 < np);

        // ====== even tile (read buf0, stage t+1 -> buf1) ======
        // ph0: reads + B(t+1)
        RDA4(aA0); RDB4(aB0, 0);
        gld16(gBn,      ldst + 98304);         gld16(gBn + q1, ldst + 98304 + 8192);
        gld16(gBn + q2, ldst + 98304 + 16384); gld16(gBn + q3, ldst + 98304 + 24576);
        LGKM0();
        PRIO1(); MF(0, 0); PRIO0();
        // ph1: reads + A(t+1)
        RDA4(aA1); RDB4(aB1, 1);
        gld16(gAn,      ldst + 65536);         gld16(gAn + q1, ldst + 65536 + 8192);
        gld16(gAn + q2, ldst + 65536 + 16384); gld16(gAn + q3, ldst + 65536 + 24576);
        LGKM0();
        PRIO1(); MF(0, 1); PRIO0();
        // ph2
        RDA4H(aA0);
        LGKM0();
        PRIO1(); MF(1, 0); PRIO0();
        // ph3
        RDA4H(aA1);
        LGKM0();
        PRIO1(); MF(1, 1); PRIO0();
        VMC(0);
        BARRIER();

        // ====== odd tile (read buf1, stage t+2 -> buf0) ======
        RDA4(aA0o); RDB4(aB0o, 0);
        if (nl) {
            gld16(gBn +      64, ldst + 32768); gld16(gBn + q1 + 64, ldst + 40960);
            gld16(gBn + q2 + 64, ldst + 49152); gld16(gBn + q3 + 64, ldst + 57344);
        }
        LGKM0();
        PRIO1(); MF(0, 0); PRIO0();
        RDA4(aA1o); RDB4(aB1o, 1);
        if (nl) {
            gld16(gAn +      64, ldst);         gld16(gAn + q1 + 64, ldst + 8192);
            gld16(gAn + q2 + 64, ldst + 16384); gld16(gAn + q3 + 64, ldst + 24576);
        }
        LGKM0();
        PRIO1(); MF(0, 1); PRIO0();
        RDA4H(aA0o);
        LGKM0();
        PRIO1(); MF(1, 0); PRIO0();
        RDA4H(aA1o);
        LGKM0();
        PRIO1(); MF(1, 1); PRIO0();
        if (nl) {
            VMC(0);
            BARRIER();
        }
        gAn += 128; gBn += 128;
    }

    // ---- epilogue: C/D layout col=lane&15, row=(lane>>4)*4+reg, nf inner --
    if constexpr (EPI == 4) {
        short* op; const float* bp; bool dt;
        if (bn < 1024)      { op = (short*)out0; bp = b0; dt = true;  }
        else if (bn < 2048) { op = out1;         bp = b1; dt = true;  }
        else                { op = out2;         bp = b2; dt = false; }
        const int cb = bn & 1023;
        float bc[4];
        #pragma unroll
        for (int nf = 0; nf < 4; ++nf) bc[nf] = bp[cb + wc * 64 + nf * 16 + fr];
        #pragma unroll
        for (int mf = 0; mf < 8; ++mf)
            #pragma unroll
            for (int rr = 0; rr < 4; ++rr) {
                const int row = bm + wr * 128 + mf * 16 + kb * 4 + rr;
                #pragma unroll
                for (int nf = 0; nf < 4; ++nf) {
                    const int cc = cb + wc * 64 + nf * 16 + fr;
                    float c = acc[mf][nf][rr] + bc[nf];
                    if (dt) c = ftanh(c) * PI_F;
                    op[(size_t)row * 1024 + cc] = f2h(c);
                }
            }
    } else {   // EPI == 3: +X residual -> fp32
        float bc[4];
        #pragma unroll
        for (int nf = 0; nf < 4; ++nf) bc[nf] = b0[bn + wc * 64 + nf * 16 + fr];
        #pragma unroll
        for (int mf = 0; mf < 8; ++mf)
            #pragma unroll
            for (int rr = 0; rr < 4; ++rr) {
                const int row = bm + wr * 128 + mf * 16 + kb * 4 + rr;
                #pragma unroll
                for (int nf = 0; nf < 4; ++nf) {
                    const int col = bn + wc * 64 + nf * 16 + fr;
                    float c = acc[mf][nf][rr] + bc[nf] + X[(size_t)row * N + col];
                    ((float*)out0)[(size_t)row * N + col] = c;
                }
            }
    }
}

// ---------------------------------------------------------------------------
// gemm128 — 128x128 tile, BK=64, 4 waves, 64KB LDS dbuf (2 blocks/CU).
// H-gate GEMM (EPI 5): gelu(acc+bg1).Wg2 -> fr-reduce -> atomicAdd gatep.
// ---------------------------------------------------------------------------
#define RDAF(areg)                                                       \
    DSR(af[0], areg, "0");    DSR(af[1], areg, "2048");                  \
    DSR(af[2], areg, "4096"); DSR(af[3], areg, "6144");
#define RDBF(areg)                                                       \
    DSR(bqs[0], areg, "0");    DSR(bqs[1], areg, "2048");                \
    DSR(bqs[2], areg, "4096"); DSR(bqs[3], areg, "6144");

#define MF16()                                                           \
    _Pragma("unroll") for (int i_ = 0; i_ < 4; ++i_)                     \
    _Pragma("unroll") for (int n_ = 0; n_ < 4; ++n_)                     \
        acc[i_][n_] = __builtin_amdgcn_mfma_f32_16x16x32_f16(            \
            af[i_], bqs[n_], acc[i_][n_], 0, 0, 0);

template<int EPI>
__global__ __launch_bounds__(256, 2)
void gemm128(const short* __restrict__ A, const short* __restrict__ Bt,
             const float* __restrict__ b0, const float* __restrict__ wg2p,
             float* __restrict__ gatep, int M, int N, int K)
{
    extern __shared__ char lds[];   // 65536

    const int tid = threadIdx.x;
    const int w = tid >> 6, l = tid & 63;
    const int wr = w >> 1, wc = w & 1;
    const int fr = l & 15, kb = l >> 4;
    const int bm = blockIdx.x * 128, bn = blockIdx.y * 128;

    const int s = fr & 7;
    const int cK0 = (((s >> 2) & 1) << 6) | (((kb ^ s) & 3) << 4);
    const int aA0e = (wr * 64 + fr) * 128 + cK0;
    const int aA1e = aA0e ^ 64;
    const int aB0e = 16384 + (wc * 64 + fr) * 128 + cK0;
    const int aB1e = aB0e ^ 64;
    const int aA0o = aA0e + 32768, aA1o = aA1e + 32768;
    const int aB0o = aB0e + 32768, aB1o = aB1e + 32768;

    const int p16 = tid * 16;
    const int sr = p16 >> 7;
    const int sc = (p16 & 127) ^ ((sr & 7) << 4);
    const short* gA = A  + (size_t)(bm + sr) * K + (sc >> 1);
    const short* gB = Bt + (size_t)(bn + sr) * K + (sc >> 1);
    char* ldA = lds + (w << 10);
    const size_t r32 = (size_t)32 * K;

    f32x4 acc[4][4] = {};
    f16x8 af[4], bqs[4];

    #pragma unroll
    for (int i = 0; i < 4; ++i) gld16(gA + i * r32, ldA + i * 4096);
    #pragma unroll
    for (int i = 0; i < 4; ++i) gld16(gB + i * r32, ldA + 16384 + i * 4096);
    VMC(0);
    BARRIER();

    const short* gAt = gA;
    const short* gBt = gB;
    const int np = K >> 7;

    for (int pp = 0; pp < np; ++pp) {
        const bool nl = (pp + 1 < np);

        RDAF(aA0e); RDBF(aB0e);
        #pragma unroll
        for (int i = 0; i < 4; ++i) gld16(gAt + 64 + i * r32, ldA + 32768 + i * 4096);
        LGKM0();
        PRIO1(); MF16(); PRIO0();
        RDAF(aA1e); RDBF(aB1e);
        #pragma unroll
        for (int i = 0; i < 4; ++i) gld16(gBt + 64 + i * r32, ldA + 49152 + i * 4096);
        LGKM0();
        PRIO1(); MF16(); PRIO0();
        VMC(0);
        BARRIER();

        RDAF(aA0o); RDBF(aB0o);
        if (nl) {
            #pragma unroll
            for (int i = 0; i < 4; ++i) gld16(gAt + 128 + i * r32, ldA + i * 4096);
        }
        LGKM0();
        PRIO1(); MF16(); PRIO0();
        RDAF(aA1o); RDBF(aB1o);
        if (nl) {
            #pragma unroll
            for (int i = 0; i < 4; ++i) gld16(gBt + 128 + i * r32, ldA + 16384 + i * 4096);
        }
        LGKM0();
        PRIO1(); MF16(); PRIO0();
        if (nl) {
            VMC(0);
            BARRIER();
        }
        gAt += 128; gBt += 128;
    }

    float bg[4], wg[4];
    #pragma unroll
    for (int nf = 0; nf < 4; ++nf) {
        const int cl = bn + wc * 64 + nf * 16 + fr;
        bg[nf] = b0[cl];
        wg[nf] = wg2p[cl];
    }
    #pragma unroll
    for (int mf = 0; mf < 4; ++mf)
        #pragma unroll
        for (int rr = 0; rr < 4; ++rr) {
            const int row = bm + wr * 64 + mf * 16 + kb * 4 + rr;
            float part = 0.f;
            #pragma unroll
            for (int nf = 0; nf < 4; ++nf) {
                float c = acc[mf][nf][rr] + bg[nf];
                float tt = 0.7978845608028654f * (c + 0.044715f * c * c * c);
                float g = 0.5f * c * (1.0f + ftanh(tt));
                part += g * wg[nf];
            }
            part += __shfl_xor(part, 1);
            part += __shfl_xor(part, 2);
            part += __shfl_xor(part, 4);
            part += __shfl_xor(part, 8);
            if (fr == 0) atomicAdd(&gatep[row], part);
        }
}

// ---------------------------------------------------------------------------
// Pass A: per-chunk sums; CSP table for cos/sin(pp). grid = B*NC = 1024.
// ---------------------------------------------------------------------------
__global__ __launch_bounds__(256)
void passA(const short* __restrict__ V, const short* __restrict__ KP,
           const short* __restrict__ CSP, f32x4* __restrict__ SI)
{
    const int bid = blockIdx.x;          // b*NC + c
    const int b = bid >> 8, c = bid & 255;
    const int d0 = threadIdx.x * 4;

    f32x4 cr = {}, ci = {}, pr = {}, pi = {};
    const size_t base = ((size_t)b * L_ + (size_t)c * CL_) * D_ + d0;
    const size_t pcs  = ((size_t)c * CL_ * D_ + d0) * 2;
    for (int ll = 0; ll < CL_; ++ll) {
        s16x4 v4  = *(const s16x4*)&V [base + (size_t)ll * D_];
        s16x4 kp4 = *(const s16x4*)&KP[base + (size_t)ll * D_];
        s16x8 c8  = *(const s16x8*)&CSP[pcs + (size_t)ll * (D_ * 2)];
        #pragma unroll
        for (int j = 0; j < 4; ++j) {
            float v = h2f(v4[j]);
            float sk, ck;
            fsincos(h2f(kp4[j]), &sk, &ck);
            float cp = h2f(c8[2 * j]), sp = h2f(c8[2 * j + 1]);
            cr[j] += v * ck; ci[j] += v * sk;
            pr[j] += v * cp; pi[j] += v * sp;
        }
    }
    const size_t sidx = ((size_t)bid << 10) + d0;
    #pragma unroll
    for (int j = 0; j < 4; ++j) {
        f32x4 o = { cr[j], ci[j], pr[j], pi[j] };
        SI[sidx + j] = o;
    }
}

// ---------------------------------------------------------------------------
// Pass B1: exclusive scan within 8-chunk segments; emits segment sums.
// ---------------------------------------------------------------------------
__global__ __launch_bounds__(256)
void passB1(f32x4* __restrict__ SI, f32x4* __restrict__ STS)
{
    const int seg = blockIdx.x & (NSEG_ - 1);
    const int t = (blockIdx.x >> 5) * 256 + threadIdx.x;  // 0..B*D-1
    const int b = t >> 10, d = t & 1023;
    f32x4 run = {};
    #pragma unroll
    for (int i = 0; i < SEGL_; ++i) {
        const int c = seg * SEGL_ + i;
        const size_t idx = ((size_t)(b * NC_ + c) << 10) + d;
        f32x4 v = SI[idx];
        SI[idx] = run;
        run += v;
    }
    STS[((size_t)(b * NSEG_ + seg) << 10) + d] = run;
}

// ---------------------------------------------------------------------------
// Pass B2: exclusive scan of segment sums (32 per (b,d)).
// ---------------------------------------------------------------------------
__global__ __launch_bounds__(256)
void passB2(f32x4* __restrict__ STS)
{
    const int t = blockIdx.x * 256 + threadIdx.x;  // 0..B*D-1
    const int b = t >> 10, d = t & 1023;
    f32x4 run = {};
    #pragma unroll
    for (int seg = 0; seg < NSEG_; ++seg) {
        const size_t idx = ((size_t)(b * NSEG_ + seg) << 10) + d;
        f32x4 v = STS[idx];
        STS[idx] = run;
        run += v;
    }
}

// ---------------------------------------------------------------------------
// Pass C v2 — wave-per-chunk, barrier-free; pure-__shfl LN reduce; register
// prefetch of next-iter loads. grid = B*NC/4 blocks x 256 thr.
// ---------------------------------------------------------------------------
__global__ __launch_bounds__(256)
void passC(const short* __restrict__ V, const short* KP,
           const short* __restrict__ QP, const short* __restrict__ CSP,
           const float* __restrict__ gatep, const float* __restrict__ bg2,
           const f32x4* __restrict__ SI, const f32x4* __restrict__ STS,
           const float* __restrict__ ln_g, const float* __restrict__ ln_b,
           short* Yb)
{
    const int w = threadIdx.x >> 6, lane = threadIdx.x & 63;
    const int gw = blockIdx.x * 4 + w;          // chunk id 0..B*NC-1
    const int b = gw >> 8, c = gw & 255;
    const int d0 = lane * 16;

    const size_t sidx = ((size_t)gw << 10) + d0;
    const size_t tidx = ((size_t)(b * NSEG_ + (c >> 3)) << 10) + d0;
    float cr[16], ci[16], pr[16], pi[16];
    #pragma unroll
    for (int j = 0; j < 16; ++j) {
        f32x4 s0 = SI[sidx + j] + STS[tidx + j];
        cr[j] = s0[0]; ci[j] = s0[1]; pr[j] = s0[2]; pi[j] = s0[3];
    }
    float gl[16], bl[16];
    #pragma unroll
    for (int j = 0; j < 16; ++j) { gl[j] = ln_g[d0 + j]; bl[j] = ln_b[d0 + j]; }
    const float bg2v = bg2[0];

    const int lbase = c * CL_;
    size_t off = ((size_t)b * L_ + lbase) * D_ + d0;
    size_t cso = ((size_t)lbase * D_ + d0) * 2;

    s16x8 v8a, v8b, k8a, k8b, q8a, q8b, c8a, c8b, c8c, c8d;
    v8a = *(const s16x8*)&V [off];      v8b = *(const s16x8*)&V [off + 8];
    k8a = *(const s16x8*)&KP[off];      k8b = *(const s16x8*)&KP[off + 8];
    q8a = *(const s16x8*)&QP[off];      q8b = *(const s16x8*)&QP[off + 8];
    c8a = *(const s16x8*)&CSP[cso];     c8b = *(const s16x8*)&CSP[cso + 8];
    c8c = *(const s16x8*)&CSP[cso + 16];c8d = *(const s16x8*)&CSP[cso + 24];
    float gpre = gatep[b * L_ + lbase];

    for (int l0 = 0; l0 < CL_; ++l0) {
        const int ll = lbase + l0;
        const size_t offn = off + D_;
        const size_t cson = cso + D_ * 2;
        s16x8 v8an = v8a, v8bn = v8b, k8an = k8a, k8bn = k8b;
        s16x8 q8an = q8a, q8bn = q8b, c8an = c8a, c8bn = c8b, c8cn = c8c, c8dn = c8d;
        float gpn = gpre;
        if (l0 + 1 < CL_) {
            v8an = *(const s16x8*)&V [offn];      v8bn = *(const s16x8*)&V [offn + 8];
            k8an = *(const s16x8*)&KP[offn];      k8bn = *(const s16x8*)&KP[offn + 8];
            q8an = *(const s16x8*)&QP[offn];      q8bn = *(const s16x8*)&QP[offn + 8];
            c8an = *(const s16x8*)&CSP[cson];     c8bn = *(const s16x8*)&CSP[cson + 8];
            c8cn = *(const s16x8*)&CSP[cson + 16];c8dn = *(const s16x8*)&CSP[cson + 24];
            gpn  = gatep[b * L_ + ll + 1];
        }

        const float gv = 1.0f / (1.0f + __expf(-(gpre + bg2v)));
        const float rs_pos = rsqrtf((float)(ll + 1));

        float u[16];
        float sm = 0.f, s2 = 0.f;
        #pragma unroll
        for (int j = 0; j < 16; ++j) {
            const short vs = (j < 8) ? v8a[j & 7] : v8b[j & 7];
            const short ks = (j < 8) ? k8a[j & 7] : k8b[j & 7];
            const short qs = (j < 8) ? q8a[j & 7] : q8b[j & 7];
            const int cj = 2 * j;
            const short cps = (cj < 8) ? c8a[cj & 7]
                             : (cj < 16) ? c8b[cj & 7]
                             : (cj < 24) ? c8c[cj & 7] : c8d[cj & 7];
            const short sps = (cj + 1 < 8) ? c8a[(cj + 1) & 7]
                             : (cj + 1 < 16) ? c8b[(cj + 1) & 7]
                             : (cj + 1 < 24) ? c8c[(cj + 1) & 7] : c8d[(cj + 1) & 7];
            float v = h2f(vs);
            float sk, ck, sq, cq;
            fsincos(h2f(ks), &sk, &ck);
            fsincos(h2f(qs), &sq, &cq);
            float cp = h2f(cps), sp = h2f(sps);
            cr[j] += v * ck; ci[j] += v * sk;
            pr[j] += v * cp; pi[j] += v * sp;
            float content = cr[j] * cq + ci[j] * sq;
            float posr    = pr[j] * cp + pi[j] * sp;
            u[j] = (gv * content + (1.0f - gv) * posr) * rs_pos;
            sm += u[j]; s2 += u[j] * u[j];
        }

        #pragma unroll
        for (int o = 32; o; o >>= 1) {
            sm += __shfl_down(sm, o);
            s2 += __shfl_down(s2, o);
        }
        sm = __shfl(sm, 0);
        s2 = __shfl(s2, 0);
        const float mu  = sm * (1.0f / D_);
        const float var = s2 * (1.0f / D_) - mu * mu;
        const float rsv = rsqrtf(var + LN_EPS_F);
        s16x8 yo0, yo1;
        #pragma unroll
        for (int j = 0; j < 8; ++j)
            yo0[j] = f2h((u[j] - mu) * rsv * gl[j] + bl[j]);
        #pragma unroll
        for (int j = 0; j < 8; ++j)
            yo1[j] = f2h((u[8 + j] - mu) * rsv * gl[8 + j] + bl[8 + j]);
        *(s16x8*)&Yb[off] = yo0;
        *(s16x8*)&Yb[off + 8] = yo1;

        off = offn; cso = cson;
        v8a = v8an; v8b = v8bn; k8a = k8an; k8b = k8bn;
        q8a = q8an; q8b = q8bn;
        c8a = c8an; c8b = c8bn; c8c = c8cn; c8d = c8dn;
        gpre = gpn;
    }
}

// ---------------------------------------------------------------------------
extern "C" void kernel_launch(void* const* d_in, const int* in_sizes, int n_in,
                              void* d_out, int out_size, void* d_ws, size_t ws_size,
                              hipStream_t stream)
{
    const float* x    = (const float*)d_in[0];
    const float* Wk   = (const float*)d_in[1];
    const float* bk   = (const float*)d_in[2];
    const float* Wq   = (const float*)d_in[3];
    const float* bq   = (const float*)d_in[4];
    const float* Wv   = (const float*)d_in[5];
    const float* bv   = (const float*)d_in[6];
    const float* ln_g = (const float*)d_in[7];
    const float* ln_b = (const float*)d_in[8];
    const float* Wo   = (const float*)d_in[9];
    const float* bo   = (const float*)d_in[10];
    const float* Wg1  = (const float*)d_in[11];
    const float* bg1  = (const float*)d_in[12];
    const float* Wg2  = (const float*)d_in[13];
    const float* bg2  = (const float*)d_in[14];
    const float* PP   = (const float*)d_in[15];

    float* out = (float*)d_out;

    const size_t BLD   = (size_t)B_ * L_ * D_;           // 16,777,216
    const size_t SZ_X  = BLD * 2;                        // 33,554,432
    const size_t SZ_R1 = (size_t)B_ * L_ * DG_ * 2;      //  8,388,608
    const size_t SZ_G1 = (size_t)D_ * DG_ * 2;           //    524,288
    const size_t SZ_GT = (size_t)B_ * L_ * 4;            //     65,536
    const size_t NEED  = SZ_X + SZ_R1 + SZ_G1 + 3 * SZ_X + SZ_GT;  // ~143.2MB
    if (ws_size < NEED) {
        hipMemcpyAsync(d_out, d_in[0], BLD * sizeof(float),
                       hipMemcpyDeviceToDevice, stream);
        return;
    }

    char* wsb = (char*)d_ws;
    short* xh   = (short*)(wsb);                          // region0: fp16 x (32MiB)
    char*  r1   = wsb + SZ_X;
    short* Wcat = (short*)r1;                             // [3072][1024] fp16
    short* Wg1T = (short*)(r1 + SZ_R1);                   // [256][1024] fp16
    short* KP   = (short*)(r1 + SZ_R1 + SZ_G1);
    short* QP   = (short*)((char*)KP + SZ_X);
    short* V    = (short*)((char*)QP + SZ_X);
    float* gatep = (float*)((char*)V + SZ_X);             // gate_pre accumulators
    // aliases (dead regions):
    f32x4* SI   = (f32x4*)(wsb);                          // 16.78MB (xh dead)
    short* CSP  = (short*)(wsb + 16777216);               // 16.78MB (xh dead)
    short* WtO  = (short*)r1;                             //  2MB (Wcat dead)
    f32x4* STS  = (f32x4*)(r1 + 2097152);                 //  2MB (Wcat dead)
    short* Yb   = KP;                                     // passC writes over KP

    const int M = B_ * L_;
    dim3 blk(256);

    // 1. conversions (x, QKV weights, gate W1; Wo/CSP deferred into dead areas)
    conv_x<<<(int)(BLD / 8 / 256), blk, 0, stream>>>(x, xh, (int)(BLD / 8));
    dim3 gT(D_ / 64, 16);
    dim3 gTg(DG_ / 64, 16);
    convT<<<gT, blk, 0, stream>>>(Wk, Wcat + (size_t)0 * D_ * D_, D_);
    convT<<<gT, blk, 0, stream>>>(Wq, Wcat + (size_t)1 * D_ * D_, D_);
    convT<<<gT, blk, 0, stream>>>(Wv, Wcat + (size_t)2 * D_ * D_, D_);
    convT<<<gTg, blk, 0, stream>>>(Wg1, Wg1T, DG_);
    hipMemsetAsync(gatep, 0, SZ_GT, stream);

    // 2. fused QKV GEMM (256² v9), then H-gate GEMM
    dim3 gQKV(M / 256, 3072 / 256);
    hipLaunchKernelGGL((mgemm256<4, short>), gQKV, dim3(512), 131072, stream,
                       xh, Wcat, nullptr, KP, QP, V, bk, bq, bv, M, 3072, D_);
    dim3 gH(M / 128, DG_ / 128);
    hipLaunchKernelGGL((gemm128<5>), gH, blk, 65536, stream,
                       xh, Wg1T, bg1, Wg2, gatep, M, DG_, D_);

    // 3. deferred Wo conversion (into dead Wcat) + CSP table (into dead xh)
    convT<<<gT, blk, 0, stream>>>(Wo, WtO, D_);
    csp_kernel<<<(int)((size_t)L_ * D_ / 4 / 256), blk, 0, stream>>>(
        PP, CSP, (int)((size_t)L_ * D_ / 4));

    // 4. scans + fused LN (sigmoid applied in passC)
    passA<<<B_ * NC_, blk, 0, stream>>>(V, KP, CSP, SI);
    passB1<<<(B_ * D_ / 256) * NSEG_, blk, 0, stream>>>(SI, STS);
    passB2<<<B_ * D_ / 256, blk, 0, stream>>>(STS);
    passC<<<B_ * NC_ / 4, blk, 0, stream>>>(V, KP, QP, CSP, gatep, bg2, SI, STS,
                                            ln_g, ln_b, Yb);

    // 5. output GEMM (+ residual), 64x4 grid = 1 exact round
    dim3 gO(M / 256, D_ / 256);
    hipLaunchKernelGGL((mgemm256<3, float>), gO, dim3(512), 131072, stream,
                       Yb, WtO, x, out, nullptr, nullptr, bo, nullptr, nullptr,
                       M, D_, D_);
}

// Round 18
// 275.470 us; speedup vs baseline: 1.4275x; 1.0275x over previous
//
#include <hip/hip_runtime.h>
#include <math.h>

#define B_ 4
#define L_ 4096
#define D_ 1024
#define DG_ 256
#define NC_ 256         // number of chunks along L
#define CL_ 16          // chunk length (L_/NC_)
#define SEGL_ 8         // chunks per passB segment
#define NSEG_ 32        // NC_/SEGL_
#define PI_F 3.14159265358979323846f
#define LN_EPS_F 1e-5f

typedef __attribute__((ext_vector_type(8))) _Float16 f16x8;
typedef __attribute__((ext_vector_type(8))) short s16x8;
typedef __attribute__((ext_vector_type(4))) short s16x4;
typedef __attribute__((ext_vector_type(4))) float f32x4;

__device__ inline short f2h(float f) { return __builtin_bit_cast(short, (_Float16)f); }
__device__ inline float h2f(short s) { return (float)__builtin_bit_cast(_Float16, s); }

__device__ inline float ftanh(float x) {
    float e = __expf(2.0f * x);
    return 1.0f - 2.0f / (e + 1.0f);
}
__device__ inline void fsincos(float x, float* s, float* c) {
    *s = __sinf(x); *c = __cosf(x);
}

__device__ inline void gld16(const void* g, void* l) {
    __builtin_amdgcn_global_load_lds(
        (const __attribute__((address_space(1))) unsigned int*)g,
        (__attribute__((address_space(3))) unsigned int*)l, 16, 0, 0);
}

// ---------------------------------------------------------------------------
// conv_x: fp32 -> fp16, 8 elems/thread
// ---------------------------------------------------------------------------
__global__ __launch_bounds__(256)
void conv_x(const float* __restrict__ x, short* __restrict__ xh, int n8)
{
    int t = blockIdx.x * 256 + threadIdx.x;
    if (t >= n8) return;
    const float4* p = (const float4*)x + (size_t)t * 2;
    float4 a = p[0], b = p[1];
    s16x8 v;
    v[0] = f2h(a.x); v[1] = f2h(a.y); v[2] = f2h(a.z); v[3] = f2h(a.w);
    v[4] = f2h(b.x); v[5] = f2h(b.y); v[6] = f2h(b.z); v[7] = f2h(b.w);
    *(s16x8*)(xh + (size_t)t * 8) = v;
}

// ---------------------------------------------------------------------------
// convT: W[1024][N] fp32 -> Th[N][1024] fp16, LDS-tiled transpose
// ---------------------------------------------------------------------------
__global__ __launch_bounds__(256)
void convT(const float* __restrict__ W, short* __restrict__ Th, int N)
{
    __shared__ float tile[64][65];
    const int n0 = blockIdx.x * 64, k0 = blockIdx.y * 64;
    const int t = threadIdx.x;
    const int r = t >> 4, c4 = (t & 15) * 4;

    #pragma unroll
    for (int i = 0; i < 4; ++i) {
        float4 v = *(const float4*)&W[(size_t)(k0 + r + i * 16) * N + n0 + c4];
        tile[r + i * 16][c4 + 0] = v.x;
        tile[r + i * 16][c4 + 1] = v.y;
        tile[r + i * 16][c4 + 2] = v.z;
        tile[r + i * 16][c4 + 3] = v.w;
    }
    __syncthreads();
    #pragma unroll
    for (int i = 0; i < 4; ++i) {
        const int n = r + i * 16;
        s16x4 o;
        o[0] = f2h(tile[c4 + 0][n]);
        o[1] = f2h(tile[c4 + 1][n]);
        o[2] = f2h(tile[c4 + 2][n]);
        o[3] = f2h(tile[c4 + 3][n]);
        *(s16x4*)&Th[(size_t)(n0 + n) * 1024 + k0 + c4] = o;
    }
}

// ---------------------------------------------------------------------------
// Sync macros: raw s_barrier; the only sched_barrier kept is rule #18's.
// ---------------------------------------------------------------------------
#define BARRIER() __builtin_amdgcn_s_barrier()
#define PRIO1() __builtin_amdgcn_s_setprio(1)
#define PRIO0() __builtin_amdgcn_s_setprio(0)
#define LGKM0() do { asm volatile("s_waitcnt lgkmcnt(0)" ::: "memory"); \
                     __builtin_amdgcn_sched_barrier(0); } while (0)
#define VMC(N) asm volatile("s_waitcnt vmcnt(" #N ")" ::: "memory")

#define DSR(dst, areg, OFS)                                              \
    asm volatile("ds_read_b128 %0, %1 offset:" OFS                       \
                 : "=v"(dst) : "v"(areg))

#define RDA4(areg)                                                       \
    DSR(af[0], areg, "0");    DSR(af[1], areg, "2048");                  \
    DSR(af[2], areg, "4096"); DSR(af[3], areg, "6144");
#define RDA4H(areg)                                                      \
    DSR(af[0], areg, "8192");  DSR(af[1], areg, "10240");                \
    DSR(af[2], areg, "12288"); DSR(af[3], areg, "14336");
#define RDB4(areg, KK)                                                   \
    DSR(bq[0][KK], areg, "0");    DSR(bq[1][KK], areg, "2048");          \
    DSR(bq[2][KK], areg, "4096"); DSR(bq[3][KK], areg, "6144");

#define MF(MG, KK)                                                       \
    _Pragma("unroll") for (int i_ = 0; i_ < 4; ++i_)                     \
    _Pragma("unroll") for (int n_ = 0; n_ < 4; ++n_)                     \
        acc[(MG)*4 + i_][n_] = __builtin_amdgcn_mfma_f32_16x16x32_f16(   \
            af[i_], bq[n_][KK], acc[(MG)*4 + i_][n_], 0, 0, 0);

// ---------------------------------------------------------------------------
// 256x256 MFMA fp16 GEMM v9 — ONE barrier per K-tile (pure double-buffer).
// Best-measured variant (r15/r17: QKV 113 µs, MfmaUtil 40%).
// EPI 3: +X residual -> fp32; 4: fused QKV (tanh*pi / tanh*pi / plain)
// ---------------------------------------------------------------------------
template<int EPI, typename OT>
__global__ __launch_bounds__(512, 2)
void mgemm256(const short* __restrict__ A, const short* __restrict__ Bt,
              const float* __restrict__ X, OT* __restrict__ out0,
              short* __restrict__ out1, short* __restrict__ out2,
              const float* __restrict__ b0, const float* __restrict__ b1,
              const float* __restrict__ b2, int M, int N, int K)
{
    extern __shared__ char lds[];   // 131072: buf0/buf1 x (A 32KB + B 32KB)

    const int tid = threadIdx.x;
    const int w = tid >> 6, l = tid & 63;
    const int wr = w >> 2, wc = w & 3;          // 2 x 4 wave grid
    const int fr = l & 15, kb = l >> 4;
    const int bm = blockIdx.x * 256, bn = blockIdx.y * 256;
    const int np = K >> 7;                      // K-tile pairs

    const int s = fr & 7;
    const int cK0 = (((s >> 2) & 1) << 6) | (((kb ^ s) & 3) << 4);
    const int aA0 = (wr << 14) + fr * 128 + cK0;
    const int aA1 = aA0 ^ 64;
    const int aB0 = 32768 + ((wc >> 1) << 14) + ((wc & 1) * 64 + fr) * 128 + cK0;
    const int aB1 = aB0 ^ 64;
    const int aA0o = aA0 + 65536, aA1o = aA1 + 65536;
    const int aB0o = aB0 + 65536, aB1o = aB1 + 65536;

    const int p0 = tid * 16;
    const int sr = p0 >> 7;
    const int sc = (p0 & 127) ^ ((sr & 7) << 4);
    const short* gA = A  + (size_t)(bm + sr) * K + (sc >> 1);
    const short* gB = Bt + (size_t)(bn + sr) * K + (sc >> 1);
    char* ldst = lds + (w << 10);
    const size_t q1 = (size_t)64 * K, q2 = 2 * q1, q3 = 3 * q1;

    f32x4 acc[8][4] = {};
    f16x8 af[4];
    f16x8 bq[4][2];

    // ---- prologue: stage tile0 into buf0 (8 loads) ----
    gld16(gA,      ldst);          gld16(gA + q1, ldst + 8192);
    gld16(gA + q2, ldst + 16384);  gld16(gA + q3, ldst + 24576);
    gld16(gB,      ldst + 32768);  gld16(gB + q1, ldst + 40960);
    gld16(gB + q2, ldst + 49152);  gld16(gB + q3, ldst + 57344);
    VMC(0);
    BARRIER();

    const short* gAn = gA + 64;     // tile (2p+1) column base
    const short* gBn = gB + 64;

    for (int pp = 0; pp < np; ++pp) {
        const bool nl = (pp + 1 < np);

        // ====== even tile (read buf0, stage t+1 -> buf1) ======
        RDA4(aA0); RDB4(aB0, 0);
        gld16(gBn,      ldst + 98304);         gld16(gBn + q1, ldst + 98304 + 8192);
        gld16(gBn + q2, ldst + 98304 + 16384); gld16(gBn + q3, ldst + 98304 + 24576);
        LGKM0();
        PRIO1(); MF(0, 0); PRIO0();
        RDA4(aA1); RDB4(aB1, 1);
        gld16(gAn,      ldst + 65536);         gld16(gAn + q1, ldst + 65536 + 8192);
        gld16(gAn + q2, ldst + 65536 + 16384); gld16(gAn + q3, ldst + 65536 + 24576);
        LGKM0();
        PRIO1(); MF(0, 1); PRIO0();
        RDA4H(aA0);
        LGKM0();
        PRIO1(); MF(1, 0); PRIO0();
        RDA4H(aA1);
        LGKM0();
        PRIO1(); MF(1, 1); PRIO0();
        VMC(0);
        BARRIER();

        // ====== odd tile (read buf1, stage t+2 -> buf0) ======
        RDA4(aA0o); RDB4(aB0o, 0);
        if (nl) {
            gld16(gBn +      64, ldst + 32768); gld16(gBn + q1 + 64, ldst + 40960);
            gld16(gBn + q2 + 64, ldst + 49152); gld16(gBn + q3 + 64, ldst + 57344);
        }
        LGKM0();
        PRIO1(); MF(0, 0); PRIO0();
        RDA4(aA1o); RDB4(aB1o, 1);
        if (nl) {
            gld16(gAn +      64, ldst);         gld16(gAn + q1 + 64, ldst + 8192);
            gld16(gAn + q2 + 64, ldst + 16384); gld16(gAn + q3 + 64, ldst + 24576);
        }
        LGKM0();
        PRIO1(); MF(0, 1); PRIO0();
        RDA4H(aA0o);
        LGKM0();
        PRIO1(); MF(1, 0); PRIO0();
        RDA4H(aA1o);
        LGKM0();
        PRIO1(); MF(1, 1); PRIO0();
        if (nl) {
            VMC(0);
            BARRIER();
        }
        gAn += 128; gBn += 128;
    }

    // ---- epilogue: C/D layout col=lane&15, row=(lane>>4)*4+reg, nf inner --
    if constexpr (EPI == 4) {
        short* op; const float* bp; bool dt;
        if (bn < 1024)      { op = (short*)out0; bp = b0; dt = true;  }
        else if (bn < 2048) { op = out1;         bp = b1; dt = true;  }
        else                { op = out2;         bp = b2; dt = false; }
        const int cb = bn & 1023;
        float bc[4];
        #pragma unroll
        for (int nf = 0; nf < 4; ++nf) bc[nf] = bp[cb + wc * 64 + nf * 16 + fr];
        #pragma unroll
        for (int mf = 0; mf < 8; ++mf)
            #pragma unroll
            for (int rr = 0; rr < 4; ++rr) {
                const int row = bm + wr * 128 + mf * 16 + kb * 4 + rr;
                #pragma unroll
                for (int nf = 0; nf < 4; ++nf) {
                    const int cc = cb + wc * 64 + nf * 16 + fr;
                    float c = acc[mf][nf][rr] + bc[nf];
                    if (dt) c = ftanh(c) * PI_F;
                    op[(size_t)row * 1024 + cc] = f2h(c);
                }
            }
    } else {   // EPI == 3: +X residual -> fp32
        float bc[4];
        #pragma unroll
        for (int nf = 0; nf < 4; ++nf) bc[nf] = b0[bn + wc * 64 + nf * 16 + fr];
        #pragma unroll
        for (int mf = 0; mf < 8; ++mf)
            #pragma unroll
            for (int rr = 0; rr < 4; ++rr) {
                const int row = bm + wr * 128 + mf * 16 + kb * 4 + rr;
                #pragma unroll
                for (int nf = 0; nf < 4; ++nf) {
                    const int col = bn + wc * 64 + nf * 16 + fr;
                    float c = acc[mf][nf][rr] + bc[nf] + X[(size_t)row * N + col];
                    ((float*)out0)[(size_t)row * N + col] = c;
                }
            }
    }
}

// ---------------------------------------------------------------------------
// gemm128 — 128x128 tile, BK=64, 4 waves, 64KB LDS dbuf (2 blocks/CU).
// H-gate GEMM (EPI 5): gelu(acc+bg1).Wg2 -> fr-reduce -> atomicAdd gatep.
// ---------------------------------------------------------------------------
#define RDAF(areg)                                                       \
    DSR(af[0], areg, "0");    DSR(af[1], areg, "2048");                  \
    DSR(af[2], areg, "4096"); DSR(af[3], areg, "6144");
#define RDBF(areg)                                                       \
    DSR(bqs[0], areg, "0");    DSR(bqs[1], areg, "2048");                \
    DSR(bqs[2], areg, "4096"); DSR(bqs[3], areg, "6144");

#define MF16()                                                           \
    _Pragma("unroll") for (int i_ = 0; i_ < 4; ++i_)                     \
    _Pragma("unroll") for (int n_ = 0; n_ < 4; ++n_)                     \
        acc[i_][n_] = __builtin_amdgcn_mfma_f32_16x16x32_f16(            \
            af[i_], bqs[n_], acc[i_][n_], 0, 0, 0);

template<int EPI>
__global__ __launch_bounds__(256, 2)
void gemm128(const short* __restrict__ A, const short* __restrict__ Bt,
             const float* __restrict__ b0, const float* __restrict__ wg2p,
             float* __restrict__ gatep, int M, int N, int K)
{
    extern __shared__ char lds[];   // 65536

    const int tid = threadIdx.x;
    const int w = tid >> 6, l = tid & 63;
    const int wr = w >> 1, wc = w & 1;
    const int fr = l & 15, kb = l >> 4;
    const int bm = blockIdx.x * 128, bn = blockIdx.y * 128;

    const int s = fr & 7;
    const int cK0 = (((s >> 2) & 1) << 6) | (((kb ^ s) & 3) << 4);
    const int aA0e = (wr * 64 + fr) * 128 + cK0;
    const int aA1e = aA0e ^ 64;
    const int aB0e = 16384 + (wc * 64 + fr) * 128 + cK0;
    const int aB1e = aB0e ^ 64;
    const int aA0o = aA0e + 32768, aA1o = aA1e + 32768;
    const int aB0o = aB0e + 32768, aB1o = aB1e + 32768;

    const int p16 = tid * 16;
    const int sr = p16 >> 7;
    const int sc = (p16 & 127) ^ ((sr & 7) << 4);
    const short* gA = A  + (size_t)(bm + sr) * K + (sc >> 1);
    const short* gB = Bt + (size_t)(bn + sr) * K + (sc >> 1);
    char* ldA = lds + (w << 10);
    const size_t r32 = (size_t)32 * K;

    f32x4 acc[4][4] = {};
    f16x8 af[4], bqs[4];

    #pragma unroll
    for (int i = 0; i < 4; ++i) gld16(gA + i * r32, ldA + i * 4096);
    #pragma unroll
    for (int i = 0; i < 4; ++i) gld16(gB + i * r32, ldA + 16384 + i * 4096);
    VMC(0);
    BARRIER();

    const short* gAt = gA;
    const short* gBt = gB;
    const int np = K >> 7;

    for (int pp = 0; pp < np; ++pp) {
        const bool nl = (pp + 1 < np);

        RDAF(aA0e); RDBF(aB0e);
        #pragma unroll
        for (int i = 0; i < 4; ++i) gld16(gAt + 64 + i * r32, ldA + 32768 + i * 4096);
        LGKM0();
        PRIO1(); MF16(); PRIO0();
        RDAF(aA1e); RDBF(aB1e);
        #pragma unroll
        for (int i = 0; i < 4; ++i) gld16(gBt + 64 + i * r32, ldA + 49152 + i * 4096);
        LGKM0();
        PRIO1(); MF16(); PRIO0();
        VMC(0);
        BARRIER();

        RDAF(aA0o); RDBF(aB0o);
        if (nl) {
            #pragma unroll
            for (int i = 0; i < 4; ++i) gld16(gAt + 128 + i * r32, ldA + i * 4096);
        }
        LGKM0();
        PRIO1(); MF16(); PRIO0();
        RDAF(aA1o); RDBF(aB1o);
        if (nl) {
            #pragma unroll
            for (int i = 0; i < 4; ++i) gld16(gBt + 128 + i * r32, ldA + 16384 + i * 4096);
        }
        LGKM0();
        PRIO1(); MF16(); PRIO0();
        if (nl) {
            VMC(0);
            BARRIER();
        }
        gAt += 128; gBt += 128;
    }

    float bg[4], wg[4];
    #pragma unroll
    for (int nf = 0; nf < 4; ++nf) {
        const int cl = bn + wc * 64 + nf * 16 + fr;
        bg[nf] = b0[cl];
        wg[nf] = wg2p[cl];
    }
    #pragma unroll
    for (int mf = 0; mf < 4; ++mf)
        #pragma unroll
        for (int rr = 0; rr < 4; ++rr) {
            const int row = bm + wr * 64 + mf * 16 + kb * 4 + rr;
            float part = 0.f;
            #pragma unroll
            for (int nf = 0; nf < 4; ++nf) {
                float c = acc[mf][nf][rr] + bg[nf];
                float tt = 0.7978845608028654f * (c + 0.044715f * c * c * c);
                float g = 0.5f * c * (1.0f + ftanh(tt));
                part += g * wg[nf];
            }
            part += __shfl_xor(part, 1);
            part += __shfl_xor(part, 2);
            part += __shfl_xor(part, 4);
            part += __shfl_xor(part, 8);
            if (fr == 0) atomicAdd(&gatep[row], part);
        }
}

// ---------------------------------------------------------------------------
// Pass A: per-chunk sums; fp32 PP read directly (no table). grid = B*NC.
// ---------------------------------------------------------------------------
__global__ __launch_bounds__(256)
void passA(const short* __restrict__ V, const short* __restrict__ KP,
           const float* __restrict__ PP, f32x4* __restrict__ SI)
{
    const int bid = blockIdx.x;          // b*NC + c
    const int b = bid >> 8, c = bid & 255;
    const int d0 = threadIdx.x * 4;

    f32x4 cr = {}, ci = {}, pr = {}, pi = {};
    const size_t base  = ((size_t)b * L_ + (size_t)c * CL_) * D_ + d0;
    const size_t pbase = (size_t)c * CL_ * D_ + d0;
    for (int ll = 0; ll < CL_; ++ll) {
        s16x4 v4  = *(const s16x4*)&V [base + (size_t)ll * D_];
        s16x4 kp4 = *(const s16x4*)&KP[base + (size_t)ll * D_];
        f32x4 pp4 = *(const f32x4*)&PP[pbase + (size_t)ll * D_];
        #pragma unroll
        for (int j = 0; j < 4; ++j) {
            float v = h2f(v4[j]);
            float sk, ck, sp, cp;
            fsincos(h2f(kp4[j]), &sk, &ck);
            fsincos(pp4[j], &sp, &cp);
            cr[j] += v * ck; ci[j] += v * sk;
            pr[j] += v * cp; pi[j] += v * sp;
        }
    }
    const size_t sidx = ((size_t)bid << 10) + d0;
    #pragma unroll
    for (int j = 0; j < 4; ++j) {
        f32x4 o = { cr[j], ci[j], pr[j], pi[j] };
        SI[sidx + j] = o;
    }
}

// ---------------------------------------------------------------------------
// Pass B1: exclusive scan within 8-chunk segments; emits segment sums.
// ---------------------------------------------------------------------------
__global__ __launch_bounds__(256)
void passB1(f32x4* __restrict__ SI, f32x4* __restrict__ STS)
{
    const int seg = blockIdx.x & (NSEG_ - 1);
    const int t = (blockIdx.x >> 5) * 256 + threadIdx.x;  // 0..B*D-1
    const int b = t >> 10, d = t & 1023;
    f32x4 run = {};
    #pragma unroll
    for (int i = 0; i < SEGL_; ++i) {
        const int c = seg * SEGL_ + i;
        const size_t idx = ((size_t)(b * NC_ + c) << 10) + d;
        f32x4 v = SI[idx];
        SI[idx] = run;
        run += v;
    }
    STS[((size_t)(b * NSEG_ + seg) << 10) + d] = run;
}

// ---------------------------------------------------------------------------
// Pass B2: exclusive scan of segment sums (32 per (b,d)).
// ---------------------------------------------------------------------------
__global__ __launch_bounds__(256)
void passB2(f32x4* __restrict__ STS)
{
    const int t = blockIdx.x * 256 + threadIdx.x;  // 0..B*D-1
    const int b = t >> 10, d = t & 1023;
    f32x4 run = {};
    #pragma unroll
    for (int seg = 0; seg < NSEG_; ++seg) {
        const size_t idx = ((size_t)(b * NSEG_ + seg) << 10) + d;
        f32x4 v = STS[idx];
        STS[idx] = run;
        run += v;
    }
}

// ---------------------------------------------------------------------------
// Pass C v2 — wave-per-chunk, barrier-free; pure-__shfl LN reduce; register
// prefetch of next-iter loads; fp32 PP read directly (no table).
// grid = B*NC/4 blocks x 256 thr.
// ---------------------------------------------------------------------------
__global__ __launch_bounds__(256)
void passC(const short* __restrict__ V, const short* KP,
           const short* __restrict__ QP, const float* __restrict__ PP,
           const float* __restrict__ gatep, const float* __restrict__ bg2,
           const f32x4* __restrict__ SI, const f32x4* __restrict__ STS,
           const float* __restrict__ ln_g, const float* __restrict__ ln_b,
           short* Yb)
{
    const int w = threadIdx.x >> 6, lane = threadIdx.x & 63;
    const int gw = blockIdx.x * 4 + w;          // chunk id 0..B*NC-1
    const int b = gw >> 8, c = gw & 255;
    const int d0 = lane * 16;

    const size_t sidx = ((size_t)gw << 10) + d0;
    const size_t tidx = ((size_t)(b * NSEG_ + (c >> 3)) << 10) + d0;
    float cr[16], ci[16], pr[16], pi[16];
    #pragma unroll
    for (int j = 0; j < 16; ++j) {
        f32x4 s0 = SI[sidx + j] + STS[tidx + j];
        cr[j] = s0[0]; ci[j] = s0[1]; pr[j] = s0[2]; pi[j] = s0[3];
    }
    float gl[16], bl[16];
    #pragma unroll
    for (int j = 0; j < 16; ++j) { gl[j] = ln_g[d0 + j]; bl[j] = ln_b[d0 + j]; }
    const float bg2v = bg2[0];

    const int lbase = c * CL_;
    size_t off = ((size_t)b * L_ + lbase) * D_ + d0;
    size_t ppo = (size_t)lbase * D_ + d0;

    s16x8 v8a, v8b, k8a, k8b, q8a, q8b;
    f32x4 ppA, ppB, ppC, ppD;
    v8a = *(const s16x8*)&V [off];      v8b = *(const s16x8*)&V [off + 8];
    k8a = *(const s16x8*)&KP[off];      k8b = *(const s16x8*)&KP[off + 8];
    q8a = *(const s16x8*)&QP[off];      q8b = *(const s16x8*)&QP[off + 8];
    ppA = *(const f32x4*)&PP[ppo];      ppB = *(const f32x4*)&PP[ppo + 4];
    ppC = *(const f32x4*)&PP[ppo + 8];  ppD = *(const f32x4*)&PP[ppo + 12];
    float gpre = gatep[b * L_ + lbase];

    for (int l0 = 0; l0 < CL_; ++l0) {
        const int ll = lbase + l0;
        const size_t offn = off + D_;
        const size_t ppon = ppo + D_;
        s16x8 v8an = v8a, v8bn = v8b, k8an = k8a, k8bn = k8b;
        s16x8 q8an = q8a, q8bn = q8b;
        f32x4 ppAn = ppA, ppBn = ppB, ppCn = ppC, ppDn = ppD;
        float gpn = gpre;
        if (l0 + 1 < CL_) {
            v8an = *(const s16x8*)&V [offn];      v8bn = *(const s16x8*)&V [offn + 8];
            k8an = *(const s16x8*)&KP[offn];      k8bn = *(const s16x8*)&KP[offn + 8];
            q8an = *(const s16x8*)&QP[offn];      q8bn = *(const s16x8*)&QP[offn + 8];
            ppAn = *(const f32x4*)&PP[ppon];      ppBn = *(const f32x4*)&PP[ppon + 4];
            ppCn = *(const f32x4*)&PP[ppon + 8];  ppDn = *(const f32x4*)&PP[ppon + 12];
            gpn  = gatep[b * L_ + ll + 1];
        }

        const float gv = 1.0f / (1.0f + __expf(-(gpre + bg2v)));
        const float rs_pos = rsqrtf((float)(ll + 1));

        float u[16];
        float sm = 0.f, s2 = 0.f;
        #pragma unroll
        for (int j = 0; j < 16; ++j) {
            const short vs = (j < 8) ? v8a[j & 7] : v8b[j & 7];
            const short ks = (j < 8) ? k8a[j & 7] : k8b[j & 7];
            const short qs = (j < 8) ? q8a[j & 7] : q8b[j & 7];
            const float ppv = (j < 4) ? ppA[j & 3]
                            : (j < 8) ? ppB[j & 3]
                            : (j < 12) ? ppC[j & 3] : ppD[j & 3];
            float v = h2f(vs);
            float sk, ck, sq, cq, sp, cp;
            fsincos(h2f(ks), &sk, &ck);
            fsincos(h2f(qs), &sq, &cq);
            fsincos(ppv, &sp, &cp);
            cr[j] += v * ck; ci[j] += v * sk;
            pr[j] += v * cp; pi[j] += v * sp;
            float content = cr[j] * cq + ci[j] * sq;
            float posr    = pr[j] * cp + pi[j] * sp;
            u[j] = (gv * content + (1.0f - gv) * posr) * rs_pos;
            sm += u[j]; s2 += u[j] * u[j];
        }

        #pragma unroll
        for (int o = 32; o; o >>= 1) {
            sm += __shfl_down(sm, o);
            s2 += __shfl_down(s2, o);
        }
        sm = __shfl(sm, 0);
        s2 = __shfl(s2, 0);
        const float mu  = sm * (1.0f / D_);
        const float var = s2 * (1.0f / D_) - mu * mu;
        const float rsv = rsqrtf(var + LN_EPS_F);
        s16x8 yo0, yo1;
        #pragma unroll
        for (int j = 0; j < 8; ++j)
            yo0[j] = f2h((u[j] - mu) * rsv * gl[j] + bl[j]);
        #pragma unroll
        for (int j = 0; j < 8; ++j)
            yo1[j] = f2h((u[8 + j] - mu) * rsv * gl[8 + j] + bl[8 + j]);
        *(s16x8*)&Yb[off] = yo0;
        *(s16x8*)&Yb[off + 8] = yo1;

        off = offn; ppo = ppon;
        v8a = v8an; v8b = v8bn; k8a = k8an; k8b = k8bn;
        q8a = q8an; q8b = q8bn;
        ppA = ppAn; ppB = ppBn; ppC = ppCn; ppD = ppDn;
        gpre = gpn;
    }
}

// ---------------------------------------------------------------------------
extern "C" void kernel_launch(void* const* d_in, const int* in_sizes, int n_in,
                              void* d_out, int out_size, void* d_ws, size_t ws_size,
                              hipStream_t stream)
{
    const float* x    = (const float*)d_in[0];
    const float* Wk   = (const float*)d_in[1];
    const float* bk   = (const float*)d_in[2];
    const float* Wq   = (const float*)d_in[3];
    const float* bq   = (const float*)d_in[4];
    const float* Wv   = (const float*)d_in[5];
    const float* bv   = (const float*)d_in[6];
    const float* ln_g = (const float*)d_in[7];
    const float* ln_b = (const float*)d_in[8];
    const float* Wo   = (const float*)d_in[9];
    const float* bo   = (const float*)d_in[10];
    const float* Wg1  = (const float*)d_in[11];
    const float* bg1  = (const float*)d_in[12];
    const float* Wg2  = (const float*)d_in[13];
    const float* bg2  = (const float*)d_in[14];
    const float* PP   = (const float*)d_in[15];

    float* out = (float*)d_out;

    const size_t BLD   = (size_t)B_ * L_ * D_;           // 16,777,216
    const size_t SZ_X  = BLD * 2;                        // 33,554,432
    const size_t SZ_R1 = (size_t)B_ * L_ * DG_ * 2;      //  8,388,608
    const size_t SZ_G1 = (size_t)D_ * DG_ * 2;           //    524,288
    const size_t SZ_GT = (size_t)B_ * L_ * 4;            //     65,536
    const size_t NEED  = SZ_X + SZ_R1 + SZ_G1 + 3 * SZ_X + SZ_GT;  // ~143.2MB
    if (ws_size < NEED) {
        hipMemcpyAsync(d_out, d_in[0], BLD * sizeof(float),
                       hipMemcpyDeviceToDevice, stream);
        return;
    }

    char* wsb = (char*)d_ws;
    short* xh   = (short*)(wsb);                          // region0: fp16 x (32MiB)
    char*  r1   = wsb + SZ_X;
    short* Wcat = (short*)r1;                             // [3072][1024] fp16
    short* Wg1T = (short*)(r1 + SZ_R1);                   // [256][1024] fp16
    short* KP   = (short*)(r1 + SZ_R1 + SZ_G1);
    short* QP   = (short*)((char*)KP + SZ_X);
    short* V    = (short*)((char*)QP + SZ_X);
    float* gatep = (float*)((char*)V + SZ_X);             // gate_pre accumulators
    // aliases (dead regions):
    f32x4* SI   = (f32x4*)(wsb);                          // 16.78MB (xh dead)
    short* WtO  = (short*)r1;                             //  2MB (Wcat dead)
    f32x4* STS  = (f32x4*)(r1 + 2097152);                 //  2MB (Wcat dead)
    short* Yb   = KP;                                     // passC writes over KP

    const int M = B_ * L_;
    dim3 blk(256);

    // 1. conversions (x, QKV weights, gate W1; Wo deferred into dead Wcat)
    conv_x<<<(int)(BLD / 8 / 256), blk, 0, stream>>>(x, xh, (int)(BLD / 8));
    dim3 gT(D_ / 64, 16);
    dim3 gTg(DG_ / 64, 16);
    convT<<<gT, blk, 0, stream>>>(Wk, Wcat + (size_t)0 * D_ * D_, D_);
    convT<<<gT, blk, 0, stream>>>(Wq, Wcat + (size_t)1 * D_ * D_, D_);
    convT<<<gT, blk, 0, stream>>>(Wv, Wcat + (size_t)2 * D_ * D_, D_);
    convT<<<gTg, blk, 0, stream>>>(Wg1, Wg1T, DG_);
    hipMemsetAsync(gatep, 0, SZ_GT, stream);

    // 2. fused QKV GEMM (256² v9), then H-gate GEMM
    dim3 gQKV(M / 256, 3072 / 256);
    hipLaunchKernelGGL((mgemm256<4, short>), gQKV, dim3(512), 131072, stream,
                       xh, Wcat, nullptr, KP, QP, V, bk, bq, bv, M, 3072, D_);
    dim3 gH(M / 128, DG_ / 128);
    hipLaunchKernelGGL((gemm128<5>), gH, blk, 65536, stream,
                       xh, Wg1T, bg1, Wg2, gatep, M, DG_, D_);

    // 3. deferred Wo conversion (into dead Wcat)
    convT<<<gT, blk, 0, stream>>>(Wo, WtO, D_);

    // 4. scans + fused LN (sigmoid applied in passC)
    passA<<<B_ * NC_, blk, 0, stream>>>(V, KP, PP, SI);
    passB1<<<(B_ * D_ / 256) * NSEG_, blk, 0, stream>>>(SI, STS);
    passB2<<<B_ * D_ / 256, blk, 0, stream>>>(STS);
    passC<<<B_ * NC_ / 4, blk, 0, stream>>>(V, KP, QP, PP, gatep, bg2, SI, STS,
                                            ln_g, ln_b, Yb);

    // 5. output GEMM (+ residual), 64x4 grid = 1 exact round
    dim3 gO(M / 256, D_ / 256);
    hipLaunchKernelGGL((mgemm256<3, float>), gO, dim3(512), 131072, stream,
                       Yb, WtO, x, out, nullptr, nullptr, bo, nullptr, nullptr,
                       M, D_, D_);
}

// Round 19
// 268.084 us; speedup vs baseline: 1.4668x; 1.0276x over previous
//
#include <hip/hip_runtime.h>
#include <math.h>

#define B_ 4
#define L_ 4096
#define D_ 1024
#define DG_ 256
#define NC_ 256         // number of chunks along L
#define CL_ 16          // chunk length (L_/NC_)
#define SEGL_ 8         // chunks per passB segment
#define NSEG_ 32        // NC_/SEGL_
#define PI_F 3.14159265358979323846f
#define LN_EPS_F 1e-5f

typedef __attribute__((ext_vector_type(8))) _Float16 f16x8;
typedef __attribute__((ext_vector_type(8))) short s16x8;
typedef __attribute__((ext_vector_type(4))) short s16x4;
typedef __attribute__((ext_vector_type(4))) float f32x4;

__device__ inline short f2h(float f) { return __builtin_bit_cast(short, (_Float16)f); }
__device__ inline float h2f(short s) { return (float)__builtin_bit_cast(_Float16, s); }

__device__ inline float ftanh(float x) {
    float e = __expf(2.0f * x);
    return 1.0f - 2.0f / (e + 1.0f);
}
__device__ inline void fsincos(float x, float* s, float* c) {
    *s = __sinf(x); *c = __cosf(x);
}

__device__ inline void gld16(const void* g, void* l) {
    __builtin_amdgcn_global_load_lds(
        (const __attribute__((address_space(1))) unsigned int*)g,
        (__attribute__((address_space(3))) unsigned int*)l, 16, 0, 0);
}

// ---------------------------------------------------------------------------
// conv_x: fp32 -> fp16, 8 elems/thread; first 16 blocks also zero gatep
// (folds the gate-accumulator memset dispatch).
// ---------------------------------------------------------------------------
__global__ __launch_bounds__(256)
void conv_x(const float* __restrict__ x, short* __restrict__ xh,
            float* __restrict__ gatep, int n8)
{
    int t = blockIdx.x * 256 + threadIdx.x;
    if (blockIdx.x < 16) {
        *(f32x4*)&gatep[(size_t)t * 4] = f32x4{0.f, 0.f, 0.f, 0.f};
    }
    if (t >= n8) return;
    const float4* p = (const float4*)x + (size_t)t * 2;
    float4 a = p[0], b = p[1];
    s16x8 v;
    v[0] = f2h(a.x); v[1] = f2h(a.y); v[2] = f2h(a.z); v[3] = f2h(a.w);
    v[4] = f2h(b.x); v[5] = f2h(b.y); v[6] = f2h(b.z); v[7] = f2h(b.w);
    *(s16x8*)(xh + (size_t)t * 8) = v;
}

// ---------------------------------------------------------------------------
// convT3: {Wk,Wq,Wv}[1024][1024] fp32 -> Wcat[z][1024][1024] fp16 transposed;
// one launch (blockIdx.z selects the source). LDS-tiled, coalesced both sides.
// ---------------------------------------------------------------------------
__global__ __launch_bounds__(256)
void convT3(const float* __restrict__ W0, const float* __restrict__ W1,
            const float* __restrict__ W2, short* __restrict__ Th)
{
    __shared__ float tile[64][65];
    const float* W = (blockIdx.z == 0) ? W0 : (blockIdx.z == 1) ? W1 : W2;
    short* dst = Th + (size_t)blockIdx.z * D_ * D_;
    const int n0 = blockIdx.x * 64, k0 = blockIdx.y * 64;
    const int t = threadIdx.x;
    const int r = t >> 4, c4 = (t & 15) * 4;

    #pragma unroll
    for (int i = 0; i < 4; ++i) {
        float4 v = *(const float4*)&W[(size_t)(k0 + r + i * 16) * D_ + n0 + c4];
        tile[r + i * 16][c4 + 0] = v.x;
        tile[r + i * 16][c4 + 1] = v.y;
        tile[r + i * 16][c4 + 2] = v.z;
        tile[r + i * 16][c4 + 3] = v.w;
    }
    __syncthreads();
    #pragma unroll
    for (int i = 0; i < 4; ++i) {
        const int n = r + i * 16;
        s16x4 o;
        o[0] = f2h(tile[c4 + 0][n]);
        o[1] = f2h(tile[c4 + 1][n]);
        o[2] = f2h(tile[c4 + 2][n]);
        o[3] = f2h(tile[c4 + 3][n]);
        *(s16x4*)&dst[(size_t)(n0 + n) * 1024 + k0 + c4] = o;
    }
}

// ---------------------------------------------------------------------------
// convT: W[1024][N] fp32 -> Th[N][1024] fp16, LDS-tiled transpose
// ---------------------------------------------------------------------------
__global__ __launch_bounds__(256)
void convT(const float* __restrict__ W, short* __restrict__ Th, int N)
{
    __shared__ float tile[64][65];
    const int n0 = blockIdx.x * 64, k0 = blockIdx.y * 64;
    const int t = threadIdx.x;
    const int r = t >> 4, c4 = (t & 15) * 4;

    #pragma unroll
    for (int i = 0; i < 4; ++i) {
        float4 v = *(const float4*)&W[(size_t)(k0 + r + i * 16) * N + n0 + c4];
        tile[r + i * 16][c4 + 0] = v.x;
        tile[r + i * 16][c4 + 1] = v.y;
        tile[r + i * 16][c4 + 2] = v.z;
        tile[r + i * 16][c4 + 3] = v.w;
    }
    __syncthreads();
    #pragma unroll
    for (int i = 0; i < 4; ++i) {
        const int n = r + i * 16;
        s16x4 o;
        o[0] = f2h(tile[c4 + 0][n]);
        o[1] = f2h(tile[c4 + 1][n]);
        o[2] = f2h(tile[c4 + 2][n]);
        o[3] = f2h(tile[c4 + 3][n]);
        *(s16x4*)&Th[(size_t)(n0 + n) * 1024 + k0 + c4] = o;
    }
}

// ---------------------------------------------------------------------------
// Sync macros: raw s_barrier; the only sched_barrier kept is rule #18's.
// ---------------------------------------------------------------------------
#define BARRIER() __builtin_amdgcn_s_barrier()
#define PRIO1() __builtin_amdgcn_s_setprio(1)
#define PRIO0() __builtin_amdgcn_s_setprio(0)
#define LGKM0() do { asm volatile("s_waitcnt lgkmcnt(0)" ::: "memory"); \
                     __builtin_amdgcn_sched_barrier(0); } while (0)
#define VMC(N) asm volatile("s_waitcnt vmcnt(" #N ")" ::: "memory")

#define DSR(dst, areg, OFS)                                              \
    asm volatile("ds_read_b128 %0, %1 offset:" OFS                       \
                 : "=v"(dst) : "v"(areg))

#define RDA4(areg)                                                       \
    DSR(af[0], areg, "0");    DSR(af[1], areg, "2048");                  \
    DSR(af[2], areg, "4096"); DSR(af[3], areg, "6144");
#define RDA4H(areg)                                                      \
    DSR(af[0], areg, "8192");  DSR(af[1], areg, "10240");                \
    DSR(af[2], areg, "12288"); DSR(af[3], areg, "14336");
#define RDB4(areg, KK)                                                   \
    DSR(bq[0][KK], areg, "0");    DSR(bq[1][KK], areg, "2048");          \
    DSR(bq[2][KK], areg, "4096"); DSR(bq[3][KK], areg, "6144");

#define MF(MG, KK)                                                       \
    _Pragma("unroll") for (int i_ = 0; i_ < 4; ++i_)                     \
    _Pragma("unroll") for (int n_ = 0; n_ < 4; ++n_)                     \
        acc[(MG)*4 + i_][n_] = __builtin_amdgcn_mfma_f32_16x16x32_f16(   \
            af[i_], bq[n_][KK], acc[(MG)*4 + i_][n_], 0, 0, 0);

// ---------------------------------------------------------------------------
// 256x256 MFMA fp16 GEMM v9 — ONE barrier per K-tile (pure double-buffer).
// Best-measured variant (QKV 113 µs, MfmaUtil 40%).
// EPI 3: +X residual -> fp32; 4: fused QKV (tanh*pi / tanh*pi / plain)
// ---------------------------------------------------------------------------
template<int EPI, typename OT>
__global__ __launch_bounds__(512, 2)
void mgemm256(const short* __restrict__ A, const short* __restrict__ Bt,
              const float* __restrict__ X, OT* __restrict__ out0,
              short* __restrict__ out1, short* __restrict__ out2,
              const float* __restrict__ b0, const float* __restrict__ b1,
              const float* __restrict__ b2, int M, int N, int K)
{
    extern __shared__ char lds[];   // 131072: buf0/buf1 x (A 32KB + B 32KB)

    const int tid = threadIdx.x;
    const int w = tid >> 6, l = tid & 63;
    const int wr = w >> 2, wc = w & 3;          // 2 x 4 wave grid
    const int fr = l & 15, kb = l >> 4;
    const int bm = blockIdx.x * 256, bn = blockIdx.y * 256;
    const int np = K >> 7;                      // K-tile pairs

    const int s = fr & 7;
    const int cK0 = (((s >> 2) & 1) << 6) | (((kb ^ s) & 3) << 4);
    const int aA0 = (wr << 14) + fr * 128 + cK0;
    const int aA1 = aA0 ^ 64;
    const int aB0 = 32768 + ((wc >> 1) << 14) + ((wc & 1) * 64 + fr) * 128 + cK0;
    const int aB1 = aB0 ^ 64;
    const int aA0o = aA0 + 65536, aA1o = aA1 + 65536;
    const int aB0o = aB0 + 65536, aB1o = aB1 + 65536;

    const int p0 = tid * 16;
    const int sr = p0 >> 7;
    const int sc = (p0 & 127) ^ ((sr & 7) << 4);
    const short* gA = A  + (size_t)(bm + sr) * K + (sc >> 1);
    const short* gB = Bt + (size_t)(bn + sr) * K + (sc >> 1);
    char* ldst = lds + (w << 10);
    const size_t q1 = (size_t)64 * K, q2 = 2 * q1, q3 = 3 * q1;

    f32x4 acc[8][4] = {};
    f16x8 af[4];
    f16x8 bq[4][2];

    // ---- prologue: stage tile0 into buf0 (8 loads) ----
    gld16(gA,      ldst);          gld16(gA + q1, ldst + 8192);
    gld16(gA + q2, ldst + 16384);  gld16(gA + q3, ldst + 24576);
    gld16(gB,      ldst + 32768);  gld16(gB + q1, ldst + 40960);
    gld16(gB + q2, ldst + 49152);  gld16(gB + q3, ldst + 57344);
    VMC(0);
    BARRIER();

    const short* gAn = gA + 64;     // tile (2p+1) column base
    const short* gBn = gB + 64;

    for (int pp = 0; pp < np; ++pp) {
        const bool nl = (pp + 1 < np);

        // ====== even tile (read buf0, stage t+1 -> buf1) ======
        RDA4(aA0); RDB4(aB0, 0);
        gld16(gBn,      ldst + 98304);         gld16(gBn + q1, ldst + 98304 + 8192);
        gld16(gBn + q2, ldst + 98304 + 16384); gld16(gBn + q3, ldst + 98304 + 24576);
        LGKM0();
        PRIO1(); MF(0, 0); PRIO0();
        RDA4(aA1); RDB4(aB1, 1);
        gld16(gAn,      ldst + 65536);         gld16(gAn + q1, ldst + 65536 + 8192);
        gld16(gAn + q2, ldst + 65536 + 16384); gld16(gAn + q3, ldst + 65536 + 24576);
        LGKM0();
        PRIO1(); MF(0, 1); PRIO0();
        RDA4H(aA0);
        LGKM0();
        PRIO1(); MF(1, 0); PRIO0();
        RDA4H(aA1);
        LGKM0();
        PRIO1(); MF(1, 1); PRIO0();
        VMC(0);
        BARRIER();

        // ====== odd tile (read buf1, stage t+2 -> buf0) ======
        RDA4(aA0o); RDB4(aB0o, 0);
        if (nl) {
            gld16(gBn +      64, ldst + 32768); gld16(gBn + q1 + 64, ldst + 40960);
            gld16(gBn + q2 + 64, ldst + 49152); gld16(gBn + q3 + 64, ldst + 57344);
        }
        LGKM0();
        PRIO1(); MF(0, 0); PRIO0();
        RDA4(aA1o); RDB4(aB1o, 1);
        if (nl) {
            gld16(gAn +      64, ldst);         gld16(gAn + q1 + 64, ldst + 8192);
            gld16(gAn + q2 + 64, ldst + 16384); gld16(gAn + q3 + 64, ldst + 24576);
        }
        LGKM0();
        PRIO1(); MF(0, 1); PRIO0();
        RDA4H(aA0o);
        LGKM0();
        PRIO1(); MF(1, 0); PRIO0();
        RDA4H(aA1o);
        LGKM0();
        PRIO1(); MF(1, 1); PRIO0();
        if (nl) {
            VMC(0);
            BARRIER();
        }
        gAn += 128; gBn += 128;
    }

    // ---- epilogue: C/D layout col=lane&15, row=(lane>>4)*4+reg, nf inner --
    if constexpr (EPI == 4) {
        short* op; const float* bp; bool dt;
        if (bn < 1024)      { op = (short*)out0; bp = b0; dt = true;  }
        else if (bn < 2048) { op = out1;         bp = b1; dt = true;  }
        else                { op = out2;         bp = b2; dt = false; }
        const int cb = bn & 1023;
        float bc[4];
        #pragma unroll
        for (int nf = 0; nf < 4; ++nf) bc[nf] = bp[cb + wc * 64 + nf * 16 + fr];
        #pragma unroll
        for (int mf = 0; mf < 8; ++mf)
            #pragma unroll
            for (int rr = 0; rr < 4; ++rr) {
                const int row = bm + wr * 128 + mf * 16 + kb * 4 + rr;
                #pragma unroll
                for (int nf = 0; nf < 4; ++nf) {
                    const int cc = cb + wc * 64 + nf * 16 + fr;
                    float c = acc[mf][nf][rr] + bc[nf];
                    if (dt) c = ftanh(c) * PI_F;
                    op[(size_t)row * 1024 + cc] = f2h(c);
                }
            }
    } else {   // EPI == 3: +X residual -> fp32
        float bc[4];
        #pragma unroll
        for (int nf = 0; nf < 4; ++nf) bc[nf] = b0[bn + wc * 64 + nf * 16 + fr];
        #pragma unroll
        for (int mf = 0; mf < 8; ++mf)
            #pragma unroll
            for (int rr = 0; rr < 4; ++rr) {
                const int row = bm + wr * 128 + mf * 16 + kb * 4 + rr;
                #pragma unroll
                for (int nf = 0; nf < 4; ++nf) {
                    const int col = bn + wc * 64 + nf * 16 + fr;
                    float c = acc[mf][nf][rr] + bc[nf] + X[(size_t)row * N + col];
                    ((float*)out0)[(size_t)row * N + col] = c;
                }
            }
    }
}

// ---------------------------------------------------------------------------
// gemm128 — 128x128 tile, BK=64, 4 waves, 64KB LDS dbuf (2 blocks/CU).
// H-gate GEMM (EPI 5): gelu(acc+bg1).Wg2 -> fr-reduce -> atomicAdd gatep.
// ---------------------------------------------------------------------------
#define RDAF(areg)                                                       \
    DSR(af[0], areg, "0");    DSR(af[1], areg, "2048");                  \
    DSR(af[2], areg, "4096"); DSR(af[3], areg, "6144");
#define RDBF(areg)                                                       \
    DSR(bqs[0], areg, "0");    DSR(bqs[1], areg, "2048");                \
    DSR(bqs[2], areg, "4096"); DSR(bqs[3], areg, "6144");

#define MF16()                                                           \
    _Pragma("unroll") for (int i_ = 0; i_ < 4; ++i_)                     \
    _Pragma("unroll") for (int n_ = 0; n_ < 4; ++n_)                     \
        acc[i_][n_] = __builtin_amdgcn_mfma_f32_16x16x32_f16(            \
            af[i_], bqs[n_], acc[i_][n_], 0, 0, 0);

template<int EPI>
__global__ __launch_bounds__(256, 2)
void gemm128(const short* __restrict__ A, const short* __restrict__ Bt,
             const float* __restrict__ b0, const float* __restrict__ wg2p,
             float* __restrict__ gatep, int M, int N, int K)
{
    extern __shared__ char lds[];   // 65536

    const int tid = threadIdx.x;
    const int w = tid >> 6, l = tid & 63;
    const int wr = w >> 1, wc = w & 1;
    const int fr = l & 15, kb = l >> 4;
    const int bm = blockIdx.x * 128, bn = blockIdx.y * 128;

    const int s = fr & 7;
    const int cK0 = (((s >> 2) & 1) << 6) | (((kb ^ s) & 3) << 4);
    const int aA0e = (wr * 64 + fr) * 128 + cK0;
    const int aA1e = aA0e ^ 64;
    const int aB0e = 16384 + (wc * 64 + fr) * 128 + cK0;
    const int aB1e = aB0e ^ 64;
    const int aA0o = aA0e + 32768, aA1o = aA1e + 32768;
    const int aB0o = aB0e + 32768, aB1o = aB1e + 32768;

    const int p16 = tid * 16;
    const int sr = p16 >> 7;
    const int sc = (p16 & 127) ^ ((sr & 7) << 4);
    const short* gA = A  + (size_t)(bm + sr) * K + (sc >> 1);
    const short* gB = Bt + (size_t)(bn + sr) * K + (sc >> 1);
    char* ldA = lds + (w << 10);
    const size_t r32 = (size_t)32 * K;

    f32x4 acc[4][4] = {};
    f16x8 af[4], bqs[4];

    #pragma unroll
    for (int i = 0; i < 4; ++i) gld16(gA + i * r32, ldA + i * 4096);
    #pragma unroll
    for (int i = 0; i < 4; ++i) gld16(gB + i * r32, ldA + 16384 + i * 4096);
    VMC(0);
    BARRIER();

    const short* gAt = gA;
    const short* gBt = gB;
    const int np = K >> 7;

    for (int pp = 0; pp < np; ++pp) {
        const bool nl = (pp + 1 < np);

        RDAF(aA0e); RDBF(aB0e);
        #pragma unroll
        for (int i = 0; i < 4; ++i) gld16(gAt + 64 + i * r32, ldA + 32768 + i * 4096);
        LGKM0();
        PRIO1(); MF16(); PRIO0();
        RDAF(aA1e); RDBF(aB1e);
        #pragma unroll
        for (int i = 0; i < 4; ++i) gld16(gBt + 64 + i * r32, ldA + 49152 + i * 4096);
        LGKM0();
        PRIO1(); MF16(); PRIO0();
        VMC(0);
        BARRIER();

        RDAF(aA0o); RDBF(aB0o);
        if (nl) {
            #pragma unroll
            for (int i = 0; i < 4; ++i) gld16(gAt + 128 + i * r32, ldA + i * 4096);
        }
        LGKM0();
        PRIO1(); MF16(); PRIO0();
        RDAF(aA1o); RDBF(aB1o);
        if (nl) {
            #pragma unroll
            for (int i = 0; i < 4; ++i) gld16(gBt + 128 + i * r32, ldA + 16384 + i * 4096);
        }
        LGKM0();
        PRIO1(); MF16(); PRIO0();
        if (nl) {
            VMC(0);
            BARRIER();
        }
        gAt += 128; gBt += 128;
    }

    float bg[4], wg[4];
    #pragma unroll
    for (int nf = 0; nf < 4; ++nf) {
        const int cl = bn + wc * 64 + nf * 16 + fr;
        bg[nf] = b0[cl];
        wg[nf] = wg2p[cl];
    }
    #pragma unroll
    for (int mf = 0; mf < 4; ++mf)
        #pragma unroll
        for (int rr = 0; rr < 4; ++rr) {
            const int row = bm + wr * 64 + mf * 16 + kb * 4 + rr;
            float part = 0.f;
            #pragma unroll
            for (int nf = 0; nf < 4; ++nf) {
                float c = acc[mf][nf][rr] + bg[nf];
                float tt = 0.7978845608028654f * (c + 0.044715f * c * c * c);
                float g = 0.5f * c * (1.0f + ftanh(tt));
                part += g * wg[nf];
            }
            part += __shfl_xor(part, 1);
            part += __shfl_xor(part, 2);
            part += __shfl_xor(part, 4);
            part += __shfl_xor(part, 8);
            if (fr == 0) atomicAdd(&gatep[row], part);
        }
}

// ---------------------------------------------------------------------------
// Pass A: per-chunk sums; fp32 PP read directly. grid = B*NC.
// ---------------------------------------------------------------------------
__global__ __launch_bounds__(256)
void passA(const short* __restrict__ V, const short* __restrict__ KP,
           const float* __restrict__ PP, f32x4* __restrict__ SI)
{
    const int bid = blockIdx.x;          // b*NC + c
    const int b = bid >> 8, c = bid & 255;
    const int d0 = threadIdx.x * 4;

    f32x4 cr = {}, ci = {}, pr = {}, pi = {};
    const size_t base  = ((size_t)b * L_ + (size_t)c * CL_) * D_ + d0;
    const size_t pbase = (size_t)c * CL_ * D_ + d0;
    for (int ll = 0; ll < CL_; ++ll) {
        s16x4 v4  = *(const s16x4*)&V [base + (size_t)ll * D_];
        s16x4 kp4 = *(const s16x4*)&KP[base + (size_t)ll * D_];
        f32x4 pp4 = *(const f32x4*)&PP[pbase + (size_t)ll * D_];
        #pragma unroll
        for (int j = 0; j < 4; ++j) {
            float v = h2f(v4[j]);
            float sk, ck, sp, cp;
            fsincos(h2f(kp4[j]), &sk, &ck);
            fsincos(pp4[j], &sp, &cp);
            cr[j] += v * ck; ci[j] += v * sk;
            pr[j] += v * cp; pi[j] += v * sp;
        }
    }
    const size_t sidx = ((size_t)bid << 10) + d0;
    #pragma unroll
    for (int j = 0; j < 4; ++j) {
        f32x4 o = { cr[j], ci[j], pr[j], pi[j] };
        SI[sidx + j] = o;
    }
}

// ---------------------------------------------------------------------------
// Pass B1: exclusive scan within 8-chunk segments; emits segment sums.
// ---------------------------------------------------------------------------
__global__ __launch_bounds__(256)
void passB1(f32x4* __restrict__ SI, f32x4* __restrict__ STS)
{
    const int seg = blockIdx.x & (NSEG_ - 1);
    const int t = (blockIdx.x >> 5) * 256 + threadIdx.x;  // 0..B*D-1
    const int b = t >> 10, d = t & 1023;
    f32x4 run = {};
    #pragma unroll
    for (int i = 0; i < SEGL_; ++i) {
        const int c = seg * SEGL_ + i;
        const size_t idx = ((size_t)(b * NC_ + c) << 10) + d;
        f32x4 v = SI[idx];
        SI[idx] = run;
        run += v;
    }
    STS[((size_t)(b * NSEG_ + seg) << 10) + d] = run;
}

// ---------------------------------------------------------------------------
// Pass B2: exclusive scan of segment sums (32 per (b,d)).
// ---------------------------------------------------------------------------
__global__ __launch_bounds__(256)
void passB2(f32x4* __restrict__ STS)
{
    const int t = blockIdx.x * 256 + threadIdx.x;  // 0..B*D-1
    const int b = t >> 10, d = t & 1023;
    f32x4 run = {};
    #pragma unroll
    for (int seg = 0; seg < NSEG_; ++seg) {
        const size_t idx = ((size_t)(b * NSEG_ + seg) << 10) + d;
        f32x4 v = STS[idx];
        STS[idx] = run;
        run += v;
    }
}

// ---------------------------------------------------------------------------
// Pass C v2 — wave-per-chunk, barrier-free; pure-__shfl LN reduce; register
// prefetch of next-iter loads; fp32 PP read directly.
// grid = B*NC/4 blocks x 256 thr.
// ---------------------------------------------------------------------------
__global__ __launch_bounds__(256)
void passC(const short* __restrict__ V, const short* KP,
           const short* __restrict__ QP, const float* __restrict__ PP,
           const float* __restrict__ gatep, const float* __restrict__ bg2,
           const f32x4* __restrict__ SI, const f32x4* __restrict__ STS,
           const float* __restrict__ ln_g, const float* __restrict__ ln_b,
           short* Yb)
{
    const int w = threadIdx.x >> 6, lane = threadIdx.x & 63;
    const int gw = blockIdx.x * 4 + w;          // chunk id 0..B*NC-1
    const int b = gw >> 8, c = gw & 255;
    const int d0 = lane * 16;

    const size_t sidx = ((size_t)gw << 10) + d0;
    const size_t tidx = ((size_t)(b * NSEG_ + (c >> 3)) << 10) + d0;
    float cr[16], ci[16], pr[16], pi[16];
    #pragma unroll
    for (int j = 0; j < 16; ++j) {
        f32x4 s0 = SI[sidx + j] + STS[tidx + j];
        cr[j] = s0[0]; ci[j] = s0[1]; pr[j] = s0[2]; pi[j] = s0[3];
    }
    float gl[16], bl[16];
    #pragma unroll
    for (int j = 0; j < 16; ++j) { gl[j] = ln_g[d0 + j]; bl[j] = ln_b[d0 + j]; }
    const float bg2v = bg2[0];

    const int lbase = c * CL_;
    size_t off = ((size_t)b * L_ + lbase) * D_ + d0;
    size_t ppo = (size_t)lbase * D_ + d0;

    s16x8 v8a, v8b, k8a, k8b, q8a, q8b;
    f32x4 ppA, ppB, ppC, ppD;
    v8a = *(const s16x8*)&V [off];      v8b = *(const s16x8*)&V [off + 8];
    k8a = *(const s16x8*)&KP[off];      k8b = *(const s16x8*)&KP[off + 8];
    q8a = *(const s16x8*)&QP[off];      q8b = *(const s16x8*)&QP[off + 8];
    ppA = *(const f32x4*)&PP[ppo];      ppB = *(const f32x4*)&PP[ppo + 4];
    ppC = *(const f32x4*)&PP[ppo + 8];  ppD = *(const f32x4*)&PP[ppo + 12];
    float gpre = gatep[b * L_ + lbase];

    for (int l0 = 0; l0 < CL_; ++l0) {
        const int ll = lbase + l0;
        const size_t offn = off + D_;
        const size_t ppon = ppo + D_;
        s16x8 v8an = v8a, v8bn = v8b, k8an = k8a, k8bn = k8b;
        s16x8 q8an = q8a, q8bn = q8b;
        f32x4 ppAn = ppA, ppBn = ppB, ppCn = ppC, ppDn = ppD;
        float gpn = gpre;
        if (l0 + 1 < CL_) {
            v8an = *(const s16x8*)&V [offn];      v8bn = *(const s16x8*)&V [offn + 8];
            k8an = *(const s16x8*)&KP[offn];      k8bn = *(const s16x8*)&KP[offn + 8];
            q8an = *(const s16x8*)&QP[offn];      q8bn = *(const s16x8*)&QP[offn + 8];
            ppAn = *(const f32x4*)&PP[ppon];      ppBn = *(const f32x4*)&PP[ppon + 4];
            ppCn = *(const f32x4*)&PP[ppon + 8];  ppDn = *(const f32x4*)&PP[ppon + 12];
            gpn  = gatep[b * L_ + ll + 1];
        }

        const float gv = 1.0f / (1.0f + __expf(-(gpre + bg2v)));
        const float rs_pos = rsqrtf((float)(ll + 1));

        float u[16];
        float sm = 0.f, s2 = 0.f;
        #pragma unroll
        for (int j = 0; j < 16; ++j) {
            const short vs = (j < 8) ? v8a[j & 7] : v8b[j & 7];
            const short ks = (j < 8) ? k8a[j & 7] : k8b[j & 7];
            const short qs = (j < 8) ? q8a[j & 7] : q8b[j & 7];
            const float ppv = (j < 4) ? ppA[j & 3]
                            : (j < 8) ? ppB[j & 3]
                            : (j < 12) ? ppC[j & 3] : ppD[j & 3];
            float v = h2f(vs);
            float sk, ck, sq, cq, sp, cp;
            fsincos(h2f(ks), &sk, &ck);
            fsincos(h2f(qs), &sq, &cq);
            fsincos(ppv, &sp, &cp);
            cr[j] += v * ck; ci[j] += v * sk;
            pr[j] += v * cp; pi[j] += v * sp;
            float content = cr[j] * cq + ci[j] * sq;
            float posr    = pr[j] * cp + pi[j] * sp;
            u[j] = (gv * content + (1.0f - gv) * posr) * rs_pos;
            sm += u[j]; s2 += u[j] * u[j];
        }

        #pragma unroll
        for (int o = 32; o; o >>= 1) {
            sm += __shfl_down(sm, o);
            s2 += __shfl_down(s2, o);
        }
        sm = __shfl(sm, 0);
        s2 = __shfl(s2, 0);
        const float mu  = sm * (1.0f / D_);
        const float var = s2 * (1.0f / D_) - mu * mu;
        const float rsv = rsqrtf(var + LN_EPS_F);
        s16x8 yo0, yo1;
        #pragma unroll
        for (int j = 0; j < 8; ++j)
            yo0[j] = f2h((u[j] - mu) * rsv * gl[j] + bl[j]);
        #pragma unroll
        for (int j = 0; j < 8; ++j)
            yo1[j] = f2h((u[8 + j] - mu) * rsv * gl[8 + j] + bl[8 + j]);
        *(s16x8*)&Yb[off] = yo0;
        *(s16x8*)&Yb[off + 8] = yo1;

        off = offn; ppo = ppon;
        v8a = v8an; v8b = v8bn; k8a = k8an; k8b = k8bn;
        q8a = q8an; q8b = q8bn;
        ppA = ppAn; ppB = ppBn; ppC = ppCn; ppD = ppDn;
        gpre = gpn;
    }
}

// ---------------------------------------------------------------------------
extern "C" void kernel_launch(void* const* d_in, const int* in_sizes, int n_in,
                              void* d_out, int out_size, void* d_ws, size_t ws_size,
                              hipStream_t stream)
{
    const float* x    = (const float*)d_in[0];
    const float* Wk   = (const float*)d_in[1];
    const float* bk   = (const float*)d_in[2];
    const float* Wq   = (const float*)d_in[3];
    const float* bq   = (const float*)d_in[4];
    const float* Wv   = (const float*)d_in[5];
    const float* bv   = (const float*)d_in[6];
    const float* ln_g = (const float*)d_in[7];
    const float* ln_b = (const float*)d_in[8];
    const float* Wo   = (const float*)d_in[9];
    const float* bo   = (const float*)d_in[10];
    const float* Wg1  = (const float*)d_in[11];
    const float* bg1  = (const float*)d_in[12];
    const float* Wg2  = (const float*)d_in[13];
    const float* bg2  = (const float*)d_in[14];
    const float* PP   = (const float*)d_in[15];

    float* out = (float*)d_out;

    const size_t BLD   = (size_t)B_ * L_ * D_;           // 16,777,216
    const size_t SZ_X  = BLD * 2;                        // 33,554,432
    const size_t SZ_R1 = (size_t)B_ * L_ * DG_ * 2;      //  8,388,608
    const size_t SZ_G1 = (size_t)D_ * DG_ * 2;           //    524,288
    const size_t SZ_GT = (size_t)B_ * L_ * 4;            //     65,536
    const size_t NEED  = SZ_X + SZ_R1 + SZ_G1 + 3 * SZ_X + SZ_GT;  // ~143.2MB
    if (ws_size < NEED) {
        hipMemcpyAsync(d_out, d_in[0], BLD * sizeof(float),
                       hipMemcpyDeviceToDevice, stream);
        return;
    }

    char* wsb = (char*)d_ws;
    short* xh   = (short*)(wsb);                          // region0: fp16 x (32MiB)
    char*  r1   = wsb + SZ_X;
    short* Wcat = (short*)r1;                             // [3072][1024] fp16
    short* Wg1T = (short*)(r1 + SZ_R1);                   // [256][1024] fp16
    short* KP   = (short*)(r1 + SZ_R1 + SZ_G1);
    short* QP   = (short*)((char*)KP + SZ_X);
    short* V    = (short*)((char*)QP + SZ_X);
    float* gatep = (float*)((char*)V + SZ_X);             // gate_pre accumulators
    // aliases (dead regions):
    f32x4* SI   = (f32x4*)(wsb);                          // 16.78MB (xh dead)
    short* WtO  = (short*)r1;                             //  2MB (Wcat dead)
    f32x4* STS  = (f32x4*)(r1 + 2097152);                 //  2MB (Wcat dead)
    short* Yb   = KP;                                     // passC writes over KP

    const int M = B_ * L_;
    dim3 blk(256);

    // 1. conversions (x [+gatep zero], QKV weights in ONE launch, gate W1)
    conv_x<<<(int)(BLD / 8 / 256), blk, 0, stream>>>(x, xh, gatep, (int)(BLD / 8));
    dim3 gT3(D_ / 64, 16, 3);
    convT3<<<gT3, blk, 0, stream>>>(Wk, Wq, Wv, Wcat);
    dim3 gTg(DG_ / 64, 16);
    convT<<<gTg, blk, 0, stream>>>(Wg1, Wg1T, DG_);

    // 2. fused QKV GEMM (256² v9), then H-gate GEMM
    dim3 gQKV(M / 256, 3072 / 256);
    hipLaunchKernelGGL((mgemm256<4, short>), gQKV, dim3(512), 131072, stream,
                       xh, Wcat, nullptr, KP, QP, V, bk, bq, bv, M, 3072, D_);
    dim3 gH(M / 128, DG_ / 128);
    hipLaunchKernelGGL((gemm128<5>), gH, blk, 65536, stream,
                       xh, Wg1T, bg1, Wg2, gatep, M, DG_, D_);

    // 3. deferred Wo conversion (into dead Wcat)
    dim3 gT(D_ / 64, 16);
    convT<<<gT, blk, 0, stream>>>(Wo, WtO, D_);

    // 4. scans + fused LN (sigmoid applied in passC)
    passA<<<B_ * NC_, blk, 0, stream>>>(V, KP, PP, SI);
    passB1<<<(B_ * D_ / 256) * NSEG_, blk, 0, stream>>>(SI, STS);
    passB2<<<B_ * D_ / 256, blk, 0, stream>>>(STS);
    passC<<<B_ * NC_ / 4, blk, 0, stream>>>(V, KP, QP, PP, gatep, bg2, SI, STS,
                                            ln_g, ln_b, Yb);

    // 5. output GEMM (+ residual), 64x4 grid = 1 exact round
    dim3 gO(M / 256, D_ / 256);
    hipLaunchKernelGGL((mgemm256<3, float>), gO, dim3(512), 131072, stream,
                       Yb, WtO, x, out, nullptr, nullptr, bo, nullptr, nullptr,
                       M, D_, D_);
}